// Round 11
// baseline (1753.690 us; speedup 1.0000x reference)
//
#include <hip/hip_runtime.h>
#include <math.h>

#define NT 12000
#define NO 24000
#define KORD 10
#define E0C 384000
#define E1C 384000
#define E2C 192000
#define INV_NT (1.0f / 12000.0f)
#define NB 94              // ceil(12000/128) adj tiles
#define NADJ ((NB * (NB + 1)) / 2)  // 4465 triangular blocks

typedef float nfloat4 __attribute__((ext_vector_type(4)));

struct __align__(8) EP { int s; float w; };  // packed edge: src index + weight

// rs/cnt layout offsets: [cd0 NT][cd1 NO][cd2 NT][cs0 NO][cs1 NT][cs2 NT]
#define OCD0 0
#define OCD1 12000
#define OCD2 36000
#define OCS0 48000
#define OCS1 72000
#define OCS2 84000

static __device__ __forceinline__ float waveSum(float v) {
  v += __shfl_xor(v, 32, 64);
  v += __shfl_xor(v, 16, 64);
  v += __shfl_xor(v, 8, 64);
  v += __shfl_xor(v, 4, 64);
  v += __shfl_xor(v, 2, 64);
  v += __shfl_xor(v, 1, 64);
  return v;
}

static __device__ __forceinline__ float scSum(const float* __restrict__ scb,
                                              int slot, int lane) {
  return waveSum(scb[slot * 64 + lane]);
}

// eta for proj head kidx from row vector txv (distributed over lanes)
static __device__ __forceinline__ float gprEta(float txv, const float* __restrict__ pwAll,
                                               const float* __restrict__ pb,
                                               const float* __restrict__ gamma,
                                               int kidx, int lane) {
  int hl = lane & 31;
  const float* pw = pwAll + (size_t)kidx * 2048;
  float pa = pb[kidx * 32 + hl];
#pragma unroll
  for (int k = 0; k < 64; ++k)
    pa = fmaf(__shfl(txv, k, 64), pw[k * 32 + hl], pa);
  float part = tanhf(pa) * gamma[hl * (KORD + 1) + kidx];
#pragma unroll
  for (int d = 16; d >= 1; d >>= 1) part += __shfl_xor(part, d, 64);
  return __shfl(part, 0, 64) * (1.0f / 32.0f);
}

// dual-acc 8-unroll CSR gather over packed edges
static __device__ __forceinline__ float gatherEP(
    const EP* __restrict__ ep, int p0, int p1,
    const float* __restrict__ X, int lane) {
  float a0 = 0.f, a1 = 0.f;
  int p = p0;
  for (; p + 7 < p1; p += 8) {
    EP e0 = ep[p], e1 = ep[p + 1], e2 = ep[p + 2], e3 = ep[p + 3];
    EP e4 = ep[p + 4], e5 = ep[p + 5], e6 = ep[p + 6], e7 = ep[p + 7];
    a0 = fmaf(X[(size_t)e0.s * 64 + lane], e0.w, a0);
    a1 = fmaf(X[(size_t)e1.s * 64 + lane], e1.w, a1);
    a0 = fmaf(X[(size_t)e2.s * 64 + lane], e2.w, a0);
    a1 = fmaf(X[(size_t)e3.s * 64 + lane], e3.w, a1);
    a0 = fmaf(X[(size_t)e4.s * 64 + lane], e4.w, a0);
    a1 = fmaf(X[(size_t)e5.s * 64 + lane], e5.w, a1);
    a0 = fmaf(X[(size_t)e6.s * 64 + lane], e6.w, a0);
    a1 = fmaf(X[(size_t)e7.s * 64 + lane], e7.w, a1);
  }
  for (; p < p1; ++p) { EP e = ep[p]; a0 = fmaf(X[(size_t)e.s * 64 + lane], e.w, a0); }
  return a0 + a1;
}

// CSR gather + deg-norm + (agg@W + b) + optional score/raw (global W)
static __device__ __forceinline__ void rowaggD(
    const float* __restrict__ X, const EP* __restrict__ ep,
    const int* __restrict__ rp, float rsdv,
    const float* __restrict__ W, const float* __restrict__ b,
    float* __restrict__ outp, int row, int lane,
    const float* fcW, const float* fcb, const float* av, float* score,
    float* __restrict__ rawAgg) {
  float acc = gatherEP(ep, rp[row], rp[row + 1], X, lane);
  if (rawAgg) rawAgg[(size_t)row * 64 + lane] = acc;
  acc *= rsdv;
  float m = b[lane];
#pragma unroll
  for (int k = 0; k < 64; ++k) m = fmaf(__shfl(acc, k, 64), W[k * 64 + lane], m);
  outp[(size_t)row * 64 + lane] = m;
  if (score) {
    float fa = fcb[lane];
#pragma unroll
    for (int k = 0; k < 64; ++k) fa = fmaf(__shfl(m, k, 64), fcW[k * 64 + lane], fa);
    float part = waveSum(tanhf(fa) * av[lane]);
    if (lane == 0) atomicAdd(&score[blockIdx.x & 63], part);
  }
}

// degree histograms (6 arrays) + input projections, fused
__global__ __launch_bounds__(256) void k_histproj(
    const int* __restrict__ sr0, const int* __restrict__ ds0,
    const int* __restrict__ sr1, const int* __restrict__ ds1,
    const int* __restrict__ sr2, const int* __restrict__ ds2,
    int* __restrict__ cnt,
    const float* __restrict__ features, const float* __restrict__ feato,
    const float* __restrict__ Wt, const float* __restrict__ bt,
    const float* __restrict__ Wo, const float* __restrict__ bo,
    float* __restrict__ Tx0t, float* __restrict__ Tx0o) {
  int gtid = blockIdx.x * 256 + threadIdx.x;
  int TOT = gridDim.x * 256;
  for (int i = gtid; i < E0C; i += TOT) {
    atomicAdd(&cnt[OCD0 + ds0[i]], 1);
    atomicAdd(&cnt[OCS0 + sr0[i]], 1);
  }
  for (int i = gtid; i < E1C; i += TOT) {
    atomicAdd(&cnt[OCD1 + ds1[i]], 1);
    atomicAdd(&cnt[OCS1 + sr1[i]], 1);
  }
  for (int i = gtid; i < E2C; i += TOT) {
    atomicAdd(&cnt[OCD2 + ds2[i]], 1);
    atomicAdd(&cnt[OCS2 + sr2[i]], 1);
  }
  int lane = threadIdx.x & 63;
  int gw = gtid >> 6, NW = TOT >> 6;
  for (int r = gw; r < NT + NO; r += NW) {
    if (r < NT) {
      const float* x = features + (size_t)r * 334;
      float a = bt[lane];
      for (int k = 0; k < 334; ++k) a = fmaf(x[k], Wt[k * 64 + lane], a);
      Tx0t[(size_t)r * 64 + lane] = a;
    } else {
      int ro = r - NT;
      const float* x = feato + (size_t)ro * 128;
      float a = bo[lane];
      for (int k = 0; k < 128; ++k) a = fmaf(x[k], Wo[k * 64 + lane], a);
      Tx0o[(size_t)ro * 64 + lane] = a;
    }
  }
}

// rs = 1/sqrt(max(cnt,1)); chunk-local exclusive scans (48 blocks)
__global__ __launch_bounds__(1024) void k_rsScan(
    const int* __restrict__ cnt, float* __restrict__ rs,
    int* __restrict__ rp0, int* __restrict__ rp1, int* __restrict__ rp2,
    int* __restrict__ ctot) {
  __shared__ int wsums[16];
  int tid = threadIdx.x, lane = tid & 63, wid = tid >> 6;
  for (int i = blockIdx.x * 1024 + tid; i < 96000; i += 48 * 1024)
    rs[i] = 1.0f / sqrtf(fmaxf((float)cnt[i], 1.0f));
  int ct = blockIdx.x;
  int rel, chunk;
  if (ct < 12) { rel = 0; chunk = ct; }
  else if (ct < 36) { rel = 1; chunk = ct - 12; }
  else { rel = 2; chunk = ct - 36; }
  int n = (rel == 1) ? NO : NT;
  const int* cdp = cnt + ((rel == 0) ? OCD0 : (rel == 1) ? OCD1 : OCD2);
  int* rpp = (rel == 0) ? rp0 : (rel == 1) ? rp1 : rp2;
  int i = chunk * 1024 + tid;
  int vI = (i < n) ? cdp[i] : 0;
  int s = vI;
#pragma unroll
  for (int d = 1; d < 64; d <<= 1) { int t = __shfl_up(s, d, 64); if (lane >= d) s += t; }
  if (lane == 63) wsums[wid] = s;
  __syncthreads();
  if (tid < 16) {
    int w = wsums[tid];
#pragma unroll
    for (int d = 1; d < 16; d <<= 1) { int t = __shfl_up(w, d, 64); if (tid >= d) w += t; }
    wsums[tid] = w;
  }
  __syncthreads();
  int wbase = wid ? wsums[wid - 1] : 0;
  if (i < n) rpp[i] = wbase + s - vI;
  if (tid == 0) ctot[rel * 40 + chunk] = wsums[15];
}

// chunk-base fix (block-local 48-entry prefix)
__global__ __launch_bounds__(256) void k_rpfix(
    int* __restrict__ rp0, int* __restrict__ rp1, int* __restrict__ rp2,
    const int* __restrict__ ctot) {
  __shared__ int cb[120];
  if (threadIdx.x == 0) {
    int b = 0;
    for (int c = 0; c < 12; ++c) { cb[c] = b; b += ctot[c]; }
    if (blockIdx.x == 0) rp0[NT] = b;
    b = 0;
    for (int c = 0; c < 24; ++c) { cb[40 + c] = b; b += ctot[40 + c]; }
    if (blockIdx.x == 0) rp1[NO] = b;
    b = 0;
    for (int c = 0; c < 12; ++c) { cb[80 + c] = b; b += ctot[80 + c]; }
    if (blockIdx.x == 0) rp2[NT] = b;
  }
  __syncthreads();
  int i = blockIdx.x * 256 + threadIdx.x;
  int TOT = gridDim.x * 256;
  for (int j = i; j < NT; j += TOT) rp0[j] += cb[j >> 10];
  for (int j = i; j < NO; j += TOT) rp1[j] += cb[40 + (j >> 10)];
  for (int j = i; j < NT; j += TOT) rp2[j] += cb[80 + (j >> 10)];
}

__global__ void k_fill(
    const int* __restrict__ sr0, const int* __restrict__ ds0,
    const int* __restrict__ sr1, const int* __restrict__ ds1,
    const int* __restrict__ sr2, const int* __restrict__ ds2,
    const int* __restrict__ rp0, const int* __restrict__ rp1,
    const int* __restrict__ rp2, int* __restrict__ fil,
    const float* __restrict__ rs,
    EP* __restrict__ ep0, EP* __restrict__ ep1, EP* __restrict__ ep2) {
  int gtid = blockIdx.x * 256 + threadIdx.x;
  int TOT = gridDim.x * 256;
  for (int e = gtid; e < E0C; e += TOT) {
    int d = ds0[e];
    int pos = rp0[d] + atomicAdd(&fil[d], 1);
    EP pk; pk.s = sr0[e]; pk.w = rs[OCS0 + pk.s];
    ep0[pos] = pk;
  }
  for (int e = gtid; e < E1C; e += TOT) {
    int d = ds1[e];
    int pos = rp1[d] + atomicAdd(&fil[12000 + d], 1);
    EP pk; pk.s = sr1[e]; pk.w = rs[OCS1 + pk.s];
    ep1[pos] = pk;
  }
  for (int e = gtid; e < E2C; e += TOT) {
    int d = ds2[e];
    int pos = rp2[d] + atomicAdd(&fil[36000 + d], 1);
    EP pk; pk.s = sr2[e]; pk.w = rs[OCS2 + pk.s];
    ep2[pos] = pk;
  }
}

// layer-1: all 3 relation GraphConvs; r2 branch also saves raw agg = A_0
__global__ __launch_bounds__(256) void k_layer1(
    const float* __restrict__ Tx0t, const float* __restrict__ Tx0o,
    const float* __restrict__ rs,
    const int* __restrict__ rp0, const EP* __restrict__ ep0,
    const int* __restrict__ rp1, const EP* __restrict__ ep1,
    const int* __restrict__ rp2, const EP* __restrict__ ep2,
    const float* __restrict__ W1r0, const float* __restrict__ b1r0,
    const float* __restrict__ W1r1, const float* __restrict__ b1r1,
    const float* __restrict__ W1r2, const float* __restrict__ b1r2,
    const float* __restrict__ a1W, const float* __restrict__ a1b,
    const float* __restrict__ a1v,
    float* __restrict__ mt0L, float* __restrict__ m2A, float* __restrict__ Tx1o,
    float* __restrict__ aggB0, float* __restrict__ sc) {
  int wid = threadIdx.x >> 6, lane = threadIdx.x & 63;
  int t = blockIdx.x * 4 + wid;
  if (t < NT) {
    rowaggD(Tx0o, ep0, rp0, rs[OCD0 + t], W1r0, b1r0, mt0L, t, lane,
            a1W, a1b, a1v, sc + 0 * 64, nullptr);
  } else if (t < 2 * NT) {
    int r = t - NT;
    rowaggD(Tx0t, ep2, rp2, rs[OCD2 + r], W1r2, b1r2, m2A, r, lane,
            a1W, a1b, a1v, sc + 1 * 64, aggB0);  // raw = G(S_0) = A_0
  } else {
    int r = t - 2 * NT;
    rowaggD(Tx0t, ep1, rp1, rs[OCD1 + r], W1r1, b1r1, Tx1o, r, lane,
            nullptr, nullptr, nullptr, nullptr, nullptr);
  }
}

// layer-1 combine + GPR heads 0,1 fused with invariant mt0b rowagg
__global__ __launch_bounds__(256) void k_comb1(
    const float* __restrict__ Tx0t, const float* __restrict__ mt0L,
    const float* __restrict__ m2A, const float* __restrict__ Tx1o,
    const float* __restrict__ rs,
    const int* __restrict__ rp0, const EP* __restrict__ ep0,
    const float* __restrict__ W2r0, const float* __restrict__ b2r0,
    const float* __restrict__ a2W, const float* __restrict__ a2b,
    const float* __restrict__ a2v,
    const float* __restrict__ projW, const float* __restrict__ projb,
    const float* __restrict__ gamma,
    float* __restrict__ Tx1t, float* __restrict__ hidden, float* __restrict__ mt0b,
    float* __restrict__ sc) {
  int wid = threadIdx.x >> 6, lane = threadIdx.x & 63;
  int t = blockIdx.x * 4 + wid;
  if (t < NT) {
    int r = t;
    size_t o = (size_t)r * 64 + lane;
    float t0 = Tx0t[o];
    float m0v = mt0L[o];
    float m2v = m2A[o];
    float s0 = scSum(sc, 0, lane) * INV_NT;
    float s1 = scSum(sc, 1, lane) * INV_NT;
    float mx = fmaxf(s0, s1);
    float e0 = expf(s0 - mx), e1 = expf(s1 - mx);
    float inv = 1.0f / (e0 + e1);
    float t1v = e0 * inv * m0v + e1 * inv * m2v;
    Tx1t[o] = t1v;
    int half = lane >> 5, hl = lane & 31;
    const float* pw = projW + (size_t)half * 2048;
    float pa = projb[half * 32 + hl];
#pragma unroll
    for (int k = 0; k < 64; ++k) {
      float x0 = __shfl(t0, k, 64);
      float x1 = __shfl(t1v, k, 64);
      pa = fmaf(half ? x1 : x0, pw[k * 32 + hl], pa);
    }
    float part = tanhf(pa) * gamma[hl * (KORD + 1) + half];
#pragma unroll
    for (int d = 16; d >= 1; d >>= 1) part += __shfl_xor(part, d, 64);
    float eta0 = __shfl(part, 0, 64) * (1.0f / 32.0f);
    float eta1 = __shfl(part, 32, 64) * (1.0f / 32.0f);
    hidden[o] = t0 * eta0 + t1v * eta1;
  } else {
    int r = t - NT;
    rowaggD(Tx1o, ep0, rp0, rs[OCD0 + r], W2r0, b2r0, mt0b, r, lane,
            a2W, a2b, a2v, sc + 2 * 64, nullptr);
  }
}

// j=1: blocks<3000 gather S_1 -> A_1 raw + mt2_1 + score slot 3 (LDS-cached W);
// blocks>=3000: invariant g0 = G(mt0b).
__global__ __launch_bounds__(256) void k_iter1(
    const float* __restrict__ Tx1t, const float* __restrict__ mt0b,
    const float* __restrict__ rsd2, const int* __restrict__ rp2,
    const EP* __restrict__ ep2,
    const float* __restrict__ W, const float* __restrict__ bW,
    const float* __restrict__ fcW, const float* __restrict__ fcb,
    const float* __restrict__ av,
    float* __restrict__ mtdst, float* __restrict__ aggB1,
    float* __restrict__ g0, float* __restrict__ scoreNew) {
  __shared__ float Wsh[4096];
  __shared__ float Fsh[4096];
  int tid = threadIdx.x;
  int wid = tid >> 6, lane = tid & 63;
  if (blockIdx.x < 3000) {
    {
      const nfloat4* Wv = reinterpret_cast<const nfloat4*>(W);
      const nfloat4* Fv = reinterpret_cast<const nfloat4*>(fcW);
      nfloat4* Ws = reinterpret_cast<nfloat4*>(Wsh);
      nfloat4* Fs = reinterpret_cast<nfloat4*>(Fsh);
#pragma unroll
      for (int i = 0; i < 4; ++i) { Ws[tid + i * 256] = Wv[tid + i * 256]; Fs[tid + i * 256] = Fv[tid + i * 256]; }
    }
    __syncthreads();
    int row = blockIdx.x * 4 + wid;
    float acc = gatherEP(ep2, rp2[row], rp2[row + 1], Tx1t, lane);
    aggB1[(size_t)row * 64 + lane] = acc;
    acc *= rsd2[row];
    float m = bW[lane];
#pragma unroll
    for (int k = 0; k < 64; ++k) m = fmaf(__shfl(acc, k, 64), Wsh[k * 64 + lane], m);
    mtdst[(size_t)row * 64 + lane] = m;
    float fa = fcb[lane];
#pragma unroll
    for (int k = 0; k < 64; ++k) fa = fmaf(__shfl(m, k, 64), Fsh[k * 64 + lane], fa);
    float part = waveSum(tanhf(fa) * av[lane]);
    if (lane == 0) atomicAdd(&scoreNew[blockIdx.x & 63], part);
  } else {
    int r = blockIdx.x * 4 + wid - NT;
    g0[(size_t)r * 64 + lane] = gatherEP(ep2, rp2[r], rp2[r + 1], mt0b, lane);
  }
}

// Fused GPR iteration j>=2 (ONE dispatch); W2r2 + a2W cached in LDS
__global__ __launch_bounds__(256) void k_iterF(
    const float* __restrict__ mt2prev, const float* __restrict__ g0,
    float* __restrict__ agg,  // read A_{j-2}, write A_j (same element, same thread)
    const float* __restrict__ mt0b, const float* __restrict__ Tsrc2,
    float* __restrict__ Tdst,
    const float* __restrict__ rsd2, const int* __restrict__ rp2,
    const EP* __restrict__ ep2,
    const float* __restrict__ W, const float* __restrict__ bW,
    const float* __restrict__ fcW, const float* __restrict__ fcb,
    const float* __restrict__ av,
    const float* __restrict__ sc, int slotPrev, float* __restrict__ scoreNew,
    const float* __restrict__ projW, const float* __restrict__ projb,
    const float* __restrict__ gamma, int kidx,
    float* __restrict__ hidden, float* __restrict__ mtdst) {
  __shared__ float Wsh[4096];
  __shared__ float Fsh[4096];
  int tid = threadIdx.x;
  {
    const nfloat4* Wv = reinterpret_cast<const nfloat4*>(W);
    const nfloat4* Fv = reinterpret_cast<const nfloat4*>(fcW);
    nfloat4* Ws = reinterpret_cast<nfloat4*>(Wsh);
    nfloat4* Fs = reinterpret_cast<nfloat4*>(Fsh);
#pragma unroll
    for (int i = 0; i < 4; ++i) { Ws[tid + i * 256] = Wv[tid + i * 256]; Fs[tid + i * 256] = Fv[tid + i * 256]; }
  }
  __syncthreads();
  int wid = tid >> 6, lane = tid & 63;
  int r = blockIdx.x * 4 + wid;
  float s0 = scSum(sc, 2, lane) * INV_NT;
  float s1 = scSum(sc, slotPrev, lane) * INV_NT;
  float mx = fmaxf(s0, s1);
  float e0 = expf(s0 - mx), e1 = expf(s1 - mx);
  float inv = 1.0f / (e0 + e1);
  float tw0 = 2.0f * e0 * inv, tw1 = 2.0f * e1 * inv;
  float gm = gatherEP(ep2, rp2[r], rp2[r + 1], mt2prev, lane);
  size_t o = (size_t)r * 64 + lane;
  float aggj = fmaf(tw0, g0[o], fmaf(tw1, gm, -agg[o]));
  agg[o] = aggj;
  float acc = aggj * rsd2[r];
  float m = bW[lane];
#pragma unroll
  for (int k = 0; k < 64; ++k) m = fmaf(__shfl(acc, k, 64), Wsh[k * 64 + lane], m);
  mtdst[o] = m;
  float fa = fcb[lane];
#pragma unroll
  for (int k = 0; k < 64; ++k) fa = fmaf(__shfl(m, k, 64), Fsh[k * 64 + lane], fa);
  float part = waveSum(tanhf(fa) * av[lane]);
  if (lane == 0) atomicAdd(&scoreNew[blockIdx.x & 63], part);
  float tj = fmaf(tw0, mt0b[o], fmaf(tw1, mt2prev[o], -Tsrc2[o]));
  Tdst[o] = tj;
  float eta = gprEta(tj, projW, projb, gamma, kidx, lane);
  hidden[o] += tj * eta;
}

// T10 fold + h=tanh -> out, logits, loss partial, stage-1 MLP for h and z_p
__global__ __launch_bounds__(256) void k_post1(
    float* __restrict__ hidden, const float* __restrict__ mt0b,
    const float* __restrict__ mt9, const float* __restrict__ T8,
    const float* __restrict__ sc,
    const float* __restrict__ projW, const float* __restrict__ projb,
    const float* __restrict__ gamma,
    const float* __restrict__ z_pre,
    const float* __restrict__ p3W, const float* __restrict__ p3b,
    const float* __restrict__ outW, const float* __restrict__ outb,
    const float* __restrict__ p1W1, const float* __restrict__ p1b1,
    float* __restrict__ outH, float* __restrict__ outLogits,
    float* __restrict__ t1, float* __restrict__ t1z,
    float* __restrict__ lossAcc) {
  int wid = threadIdx.x >> 6, lane = threadIdx.x & 63;
  int row = blockIdx.x * 4 + wid;
  size_t o = (size_t)row * 64 + lane;
  float s0 = scSum(sc, 2, lane) * INV_NT;
  float s1 = scSum(sc, 11, lane) * INV_NT;
  float mx = fmaxf(s0, s1);
  float e0 = expf(s0 - mx), e1 = expf(s1 - mx);
  float inv = 1.0f / (e0 + e1);
  float tw0 = 2.0f * e0 * inv, tw1 = 2.0f * e1 * inv;
  float t10 = fmaf(tw0, mt0b[o], fmaf(tw1, mt9[o], -T8[o]));
  float eta = gprEta(t10, projW, projb, gamma, KORD, lane);
  float hfin = hidden[o] + t10 * eta;
  hidden[o] = hfin;  // adj reads this
  float hv = tanhf(hfin);
  outH[o] = hv;
  const float* zr = z_pre + (size_t)row * 128;
  float zpv = p3b[lane];
  for (int k = 0; k < 128; ++k) zpv = fmaf(zr[k], p3W[k * 64 + lane], zpv);
  float hm = waveSum(hv) * (1.0f / 64.0f);
  float zm = waveSum(zpv) * (1.0f / 64.0f);
  float cv = waveSum((hv - hm) * (zpv - zm)) * (1.0f / 64.0f);
  if (lane == 0) atomicAdd(&lossAcc[blockIdx.x & 63], cv);
#pragma unroll
  for (int j = 0; j < 3; ++j) {
    float pj = waveSum(hv * outW[lane * 3 + j]);
    if (lane == 0) outLogits[row * 3 + j] = pj + outb[j];
  }
  float a0 = p1b1[lane], a1 = p1b1[64 + lane];
  float z0 = a0, z1 = a1;
#pragma unroll
  for (int k = 0; k < 64; ++k) {
    float hk = __shfl(hv, k, 64);
    float zk = __shfl(zpv, k, 64);
    float wlo = p1W1[k * 128 + lane], whi = p1W1[k * 128 + 64 + lane];
    a0 = fmaf(hk, wlo, a0); a1 = fmaf(hk, whi, a1);
    z0 = fmaf(zk, wlo, z0); z1 = fmaf(zk, whi, z1);
  }
  t1[(size_t)row * 128 + lane] = fmaxf(a0, 0.f);
  t1[(size_t)row * 128 + 64 + lane] = fmaxf(a1, 0.f);
  t1z[(size_t)row * 128 + lane] = fmaxf(z0, 0.f);
  t1z[(size_t)row * 128 + 64 + lane] = fmaxf(z1, 0.f);
}

// Fused: blocks [0,NADJ) = C=H@H^T triangular tiles (16-deep k phases, plain
// stores through L2); blocks >= NADJ = stage-2 MLP + loss finalize.
__global__ __launch_bounds__(256) void k_adjpost(
    const float* __restrict__ H, float* __restrict__ C, int N,
    const float* __restrict__ t1, const float* __restrict__ t1z,
    const float* __restrict__ p1W2, const float* __restrict__ p1b2,
    float* __restrict__ xpre, float* __restrict__ zpre1,
    const float* __restrict__ lossAcc, float* __restrict__ outLoss) {
  __shared__ float sh[4224];  // As = sh[0..2111] (16x132), Bs = sh[2112..4223]
  int b = blockIdx.x;
  if (b < NADJ) {
    int bi = 0, idx = b, rowlen = NB;
    while (idx >= rowlen) { idx -= rowlen; --rowlen; ++bi; }
    int bj = bi + idx;
    int tid = threadIdx.x;
    int tx = tid & 15, ty = tid >> 4;
    int rb = tid & 127, halfq = tid >> 7;  // load indexing
    float acc[8][8] = {};
    for (int kt = 0; kt < 64; kt += 16) {
      {
        int gi = bi * 128 + rb;
        int gj = bj * 128 + rb;
#pragma unroll
        for (int l = 0; l < 2; ++l) {
          int kk = (halfq * 2 + l) * 4;
          float4 a = (gi < N) ? *reinterpret_cast<const float4*>(&H[(size_t)gi * 64 + kt + kk])
                              : make_float4(0.f, 0.f, 0.f, 0.f);
          sh[(kk + 0) * 132 + rb] = a.x; sh[(kk + 1) * 132 + rb] = a.y;
          sh[(kk + 2) * 132 + rb] = a.z; sh[(kk + 3) * 132 + rb] = a.w;
          float4 bb = (gj < N) ? *reinterpret_cast<const float4*>(&H[(size_t)gj * 64 + kt + kk])
                               : make_float4(0.f, 0.f, 0.f, 0.f);
          sh[2112 + (kk + 0) * 132 + rb] = bb.x; sh[2112 + (kk + 1) * 132 + rb] = bb.y;
          sh[2112 + (kk + 2) * 132 + rb] = bb.z; sh[2112 + (kk + 3) * 132 + rb] = bb.w;
        }
      }
      __syncthreads();
#pragma unroll 8
      for (int k = 0; k < 16; ++k) {
        float4 a0 = *reinterpret_cast<const float4*>(&sh[k * 132 + ty * 4]);
        float4 a1 = *reinterpret_cast<const float4*>(&sh[k * 132 + 64 + ty * 4]);
        float4 b0 = *reinterpret_cast<const float4*>(&sh[2112 + k * 132 + tx * 4]);
        float4 b1 = *reinterpret_cast<const float4*>(&sh[2112 + k * 132 + 64 + tx * 4]);
        float av[8] = {a0.x, a0.y, a0.z, a0.w, a1.x, a1.y, a1.z, a1.w};
        float bv[8] = {b0.x, b0.y, b0.z, b0.w, b1.x, b1.y, b1.z, b1.w};
#pragma unroll
        for (int i = 0; i < 8; ++i)
#pragma unroll
          for (int j = 0; j < 8; ++j) acc[i][j] = fmaf(av[i], bv[j], acc[i][j]);
      }
      __syncthreads();
    }
    // normal-orientation stores (coalesced 256B/wave, plain through L2)
#pragma unroll
    for (int g = 0; g < 2; ++g) {
#pragma unroll
      for (int i = 0; i < 4; ++i) {
        int gr = bi * 128 + g * 64 + ty * 4 + i;
        if (gr >= N) continue;
#pragma unroll
        for (int h = 0; h < 2; ++h) {
          int gc = bj * 128 + h * 64 + tx * 4;
          if (gc >= N) continue;
          nfloat4 vv = {acc[g * 4 + i][h * 4 + 0], acc[g * 4 + i][h * 4 + 1],
                        acc[g * 4 + i][h * 4 + 2], acc[g * 4 + i][h * 4 + 3]};
          *reinterpret_cast<nfloat4*>(&C[(size_t)gr * N + gc]) = vv;
        }
      }
    }
    if (bi != bj) {
      // transpose tiles via LDS staging (reuse sh: 64*65=4160 <= 4224 floats)
      float* T = sh;
      int cc = tid >> 4, f4 = tid & 15;
#pragma unroll
      for (int g = 0; g < 2; ++g) {
#pragma unroll
        for (int h = 0; h < 2; ++h) {
          __syncthreads();
#pragma unroll
          for (int i = 0; i < 4; ++i) {
            int r = ty * 4 + i;
#pragma unroll
            for (int j = 0; j < 4; ++j)
              T[r * 65 + tx * 4 + j] = acc[g * 4 + i][h * 4 + j];
          }
          __syncthreads();
          int gr0 = bi * 128 + g * 64 + f4 * 4;
#pragma unroll
          for (int c0 = 0; c0 < 64; c0 += 16) {
            int c = c0 + cc;
            int gc = bj * 128 + h * 64 + c;
            if (gc < N) {
              nfloat4 v = {T[(f4 * 4 + 0) * 65 + c], T[(f4 * 4 + 1) * 65 + c],
                           T[(f4 * 4 + 2) * 65 + c], T[(f4 * 4 + 3) * 65 + c]};
              *reinterpret_cast<nfloat4*>(&C[(size_t)gc * N + gr0]) = v;
            }
          }
        }
      }
    }
    return;
  }
  // ---- post2 part ----
  int qb = b - NADJ;  // 0..1499
  if (qb == 0 && threadIdx.x < 64) {
    float v = waveSum(lossAcc[threadIdx.x]);
    if (threadIdx.x == 0) {
      float s = v * (1.0f / NT);
      outLoss[0] = s * s;  // loss_dis1 (1-row HSIC) is exactly 0
    }
  }
  int wid = threadIdx.x >> 6, lane = threadIdx.x & 63;
  int q = qb * 4 + wid;  // 0..5999
  bool isz = q >= 3000;
  int r0 = (isz ? q - 3000 : q) * 4;
  const float* T = isz ? t1z : t1;
  float* D = isz ? zpre1 : xpre;
  float lo[4], hi[4];
#pragma unroll
  for (int rr = 0; rr < 4; ++rr) {
    lo[rr] = T[(size_t)(r0 + rr) * 128 + lane];
    hi[rr] = T[(size_t)(r0 + rr) * 128 + 64 + lane];
  }
  for (int c0 = 0; c0 < 384; c0 += 64) {
    int c = c0 + lane;
    bool ok = c < 334;
    float bb = ok ? p1b2[c] : 0.f;
    float acc0 = bb, acc1 = bb, acc2 = bb, acc3 = bb;
    for (int k = 0; k < 64; ++k) {
      float w = ok ? p1W2[k * 334 + c] : 0.f;
      acc0 = fmaf(__shfl(lo[0], k, 64), w, acc0);
      acc1 = fmaf(__shfl(lo[1], k, 64), w, acc1);
      acc2 = fmaf(__shfl(lo[2], k, 64), w, acc2);
      acc3 = fmaf(__shfl(lo[3], k, 64), w, acc3);
    }
    for (int k = 0; k < 64; ++k) {
      float w = ok ? p1W2[(64 + k) * 334 + c] : 0.f;
      acc0 = fmaf(__shfl(hi[0], k, 64), w, acc0);
      acc1 = fmaf(__shfl(hi[1], k, 64), w, acc1);
      acc2 = fmaf(__shfl(hi[2], k, 64), w, acc2);
      acc3 = fmaf(__shfl(hi[3], k, 64), w, acc3);
    }
    if (ok) {
      D[(size_t)(r0 + 0) * 334 + c] = tanhf(acc0);
      D[(size_t)(r0 + 1) * 334 + c] = tanhf(acc1);
      D[(size_t)(r0 + 2) * 334 + c] = tanhf(acc2);
      D[(size_t)(r0 + 3) * 334 + c] = tanhf(acc3);
    }
  }
}

extern "C" void kernel_launch(void* const* d_in, const int* in_sizes, int n_in,
                              void* d_out, int out_size, void* d_ws, size_t ws_size,
                              hipStream_t stream) {
  const float* features_v1 = (const float*)d_in[0];
  const float* feat_other = (const float*)d_in[1];
  const float* z_pre = (const float*)d_in[2];
  const float* Wt = (const float*)d_in[3];  const float* bt = (const float*)d_in[4];
  const float* Wo = (const float*)d_in[5];  const float* bo = (const float*)d_in[6];
  const float* W1r0 = (const float*)d_in[7];  const float* b1r0 = (const float*)d_in[8];
  const float* W1r1 = (const float*)d_in[9];  const float* b1r1 = (const float*)d_in[10];
  const float* W1r2 = (const float*)d_in[11]; const float* b1r2 = (const float*)d_in[12];
  const float* a1W = (const float*)d_in[13]; const float* a1b = (const float*)d_in[14];
  const float* a1v = (const float*)d_in[15];
  const float* W2r0 = (const float*)d_in[16]; const float* b2r0 = (const float*)d_in[17];
  // d_in[18]/d_in[19] (W2r1/b2r1) feed only the discarded loop out_o — unused.
  const float* W2r2 = (const float*)d_in[20]; const float* b2r2 = (const float*)d_in[21];
  const float* a2W = (const float*)d_in[22]; const float* a2b = (const float*)d_in[23];
  const float* a2v = (const float*)d_in[24];
  const float* projW = (const float*)d_in[25]; const float* projb = (const float*)d_in[26];
  const float* gamma = (const float*)d_in[27];
  const float* p3W = (const float*)d_in[28]; const float* p3b = (const float*)d_in[29];
  const float* p1W1 = (const float*)d_in[30]; const float* p1b1 = (const float*)d_in[31];
  const float* p1W2 = (const float*)d_in[32]; const float* p1b2 = (const float*)d_in[33];
  const float* outW = (const float*)d_in[34]; const float* outb = (const float*)d_in[35];
  const int* sr0 = (const int*)d_in[36]; const int* ds0 = (const int*)d_in[37];
  const int* sr1 = (const int*)d_in[38]; const int* ds1 = (const int*)d_in[39];
  const int* sr2 = (const int*)d_in[40]; const int* ds2 = (const int*)d_in[41];

  float* out = (float*)d_out;
  const size_t LOGITS_OFF = 0;
  const size_t H_OFF = (size_t)NT * 3;
  const size_t XPRE_OFF = H_OFF + (size_t)NT * 64;
  const size_t ZPRE_OFF = XPRE_OFF + (size_t)NT * 334;
  const size_t ADJ_OFF = ZPRE_OFF + (size_t)NT * 334;
  const size_t LOSS_OFF = ADJ_OFF + (size_t)NT * NT;

  float* ws = (float*)d_ws;
  size_t o = 0;
  auto alloc = [&](size_t n) { float* p = ws + o; o += n; return p; };
  float* Tbuf0 = alloc((size_t)NT * 64);   // S_0 (= Tx0t)
  float* Tbuf1 = alloc((size_t)NT * 64);   // S_1
  float* Tbuf2 = alloc((size_t)NT * 64);
  float* Tx0o = alloc((size_t)NO * 64);
  float* Tx1o = alloc((size_t)NO * 64);
  float* mt0L = alloc((size_t)NT * 64);
  float* mt0b = alloc((size_t)NT * 64);
  float* m2A  = alloc((size_t)NT * 64);
  float* m2B  = alloc((size_t)NT * 64);
  float* hidden = alloc((size_t)NT * 64);
  float* t1   = alloc((size_t)NT * 128);
  float* t1z  = alloc((size_t)NT * 128);
  float* g0   = alloc((size_t)NT * 64);   // G(mt0b), loop-invariant
  float* aggB0 = alloc((size_t)NT * 64);  // A_{even}
  float* aggB1 = alloc((size_t)NT * 64);  // A_{odd}
  float* rs   = alloc(96000);
  float* sc   = alloc(1088);  // memset region starts here
  int* cnt = (int*)(ws + o); o += 96000;
  int* fil = (int*)(ws + o); o += 48000;
  int* rp0 = (int*)(ws + o); o += NT + 1;
  int* rp1 = (int*)(ws + o); o += NO + 1;
  int* rp2 = (int*)(ws + o); o += NT + 1;
  int* ctot = (int*)(ws + o); o += 120;
  o = (o + 1) & ~(size_t)1;  // 8-byte align for EP arrays
  EP* ep0 = (EP*)(ws + o); o += (size_t)E0C * 2;
  EP* ep1 = (EP*)(ws + o); o += (size_t)E1C * 2;
  EP* ep2 = (EP*)(ws + o); o += (size_t)E2C * 2;

  // zero accumulators: sc(1088) + cnt(96000) + fil(48000), contiguous
  (void)hipMemsetAsync(sc, 0, (1088 + 96000 + 48000) * sizeof(float), stream);

  k_histproj<<<2048, 256, 0, stream>>>(sr0, ds0, sr1, ds1, sr2, ds2, cnt,
                                       features_v1, feat_other, Wt, bt, Wo, bo,
                                       Tbuf0, Tx0o);
  k_rsScan<<<48, 1024, 0, stream>>>(cnt, rs, rp0, rp1, rp2, ctot);
  k_rpfix<<<256, 256, 0, stream>>>(rp0, rp1, rp2, ctot);
  k_fill<<<2048, 256, 0, stream>>>(sr0, ds0, sr1, ds1, sr2, ds2, rp0, rp1, rp2,
                                   fil, rs, ep0, ep1, ep2);
  k_layer1<<<12000, 256, 0, stream>>>(Tbuf0, Tx0o, rs,
                                      rp0, ep0, rp1, ep1, rp2, ep2,
                                      W1r0, b1r0, W1r1, b1r1, W1r2, b1r2,
                                      a1W, a1b, a1v, mt0L, m2A, Tx1o, aggB0, sc);
  k_comb1<<<6000, 256, 0, stream>>>(Tbuf0, mt0L, m2A, Tx1o, rs, rp0, ep0,
                                    W2r0, b2r0, a2W, a2b, a2v,
                                    projW, projb, gamma,
                                    Tbuf1, hidden, mt0b, sc);

  float* Tb[3] = {Tbuf0, Tbuf1, Tbuf2};
  float* Mb[2] = {m2A, m2B};
  float* Ab[2] = {aggB0, aggB1};
  const float* rsd2 = rs + OCD2;
  // j=1: gather S_1 -> A_1 + mt2_1 (Mb[1]) + score slot 3; also g0 = G(mt0b)
  k_iter1<<<6000, 256, 0, stream>>>(Tbuf1, mt0b, rsd2, rp2, ep2,
                                    W2r2, b2r2, a2W, a2b, a2v,
                                    Mb[1], aggB1, g0, sc + 3 * 64);
  for (int j = 2; j <= 9; ++j) {
    k_iterF<<<3000, 256, 0, stream>>>(Mb[(j - 1) & 1], g0, Ab[j & 1],
                                      mt0b, Tb[(j - 2) % 3], Tb[j % 3],
                                      rsd2, rp2, ep2, W2r2, b2r2,
                                      a2W, a2b, a2v, sc, 2 + j - 1,
                                      sc + (2 + j) * 64,
                                      projW, projb, gamma, j,
                                      hidden, Mb[j & 1]);
  }
  // S_9 in Tb[0]; S_8 in Tb[2]; mt2_9 in Mb[1]

  k_post1<<<3000, 256, 0, stream>>>(hidden, mt0b, Mb[1], Tb[2], sc,
                                    projW, projb, gamma, z_pre, p3W, p3b,
                                    outW, outb, p1W1, p1b1,
                                    out + H_OFF, out + LOGITS_OFF, t1, t1z,
                                    sc + 12 * 64);
  k_adjpost<<<NADJ + 1500, 256, 0, stream>>>(hidden, out + ADJ_OFF, NT,
                                             t1, t1z, p1W2, p1b2,
                                             out + XPRE_OFF, out + ZPRE_OFF,
                                             sc + 12 * 64, out + LOSS_OFF);
}

// Round 12
// 1106.601 us; speedup vs baseline: 1.5848x; 1.5848x over previous
//
#include <hip/hip_runtime.h>
#include <math.h>

#define NT 12000
#define NO 24000
#define KORD 10
#define E0C 384000
#define E1C 384000
#define E2C 192000
#define INV_NT (1.0f / 12000.0f)
#define NB 94              // ceil(12000/128) adj tiles
#define NADJ ((NB * (NB + 1)) / 2)  // 4465 triangular blocks
#define SCSTRIDE 1024      // one score slot = 64 buckets x 16-float stride

typedef float nfloat4 __attribute__((ext_vector_type(4)));

struct __align__(8) EP { int s; float w; };  // packed edge: src index + weight

// rs/cnt layout offsets: [cd0 NT][cd1 NO][cd2 NT][cs0 NO][cs1 NT][cs2 NT]
#define OCD0 0
#define OCD1 12000
#define OCD2 36000
#define OCS0 48000
#define OCS1 72000
#define OCS2 84000

static __device__ __forceinline__ float waveSum(float v) {
  v += __shfl_xor(v, 32, 64);
  v += __shfl_xor(v, 16, 64);
  v += __shfl_xor(v, 8, 64);
  v += __shfl_xor(v, 4, 64);
  v += __shfl_xor(v, 2, 64);
  v += __shfl_xor(v, 1, 64);
  return v;
}

// sum of a 64-bucket score slot (bucket i at stride 16 => 1 cache line each)
static __device__ __forceinline__ float scSum(const float* __restrict__ scb,
                                              int slot, int lane) {
  return waveSum(scb[slot * SCSTRIDE + lane * 16]);
}

// eta for proj head kidx; row vector in wave-local LDS row smrow[0..63]
static __device__ __forceinline__ float gprEta(const float* __restrict__ smrow,
                                               const float* __restrict__ pwAll,
                                               const float* __restrict__ pb,
                                               const float* __restrict__ gamma,
                                               int kidx, int lane) {
  int hl = lane & 31;
  const float* pw = pwAll + (size_t)kidx * 2048;
  float pa = pb[kidx * 32 + hl];
#pragma unroll 8
  for (int k = 0; k < 64; ++k)
    pa = fmaf(smrow[k], pw[k * 32 + hl], pa);
  float part = tanhf(pa) * gamma[hl * (KORD + 1) + kidx];
#pragma unroll
  for (int d = 16; d >= 1; d >>= 1) part += __shfl_xor(part, d, 64);
  return __shfl(part, 0, 64) * (1.0f / 32.0f);
}

// dual-acc 8-unroll CSR gather over packed edges
static __device__ __forceinline__ float gatherEP(
    const EP* __restrict__ ep, int p0, int p1,
    const float* __restrict__ X, int lane) {
  float a0 = 0.f, a1 = 0.f;
  int p = p0;
  for (; p + 7 < p1; p += 8) {
    EP e0 = ep[p], e1 = ep[p + 1], e2 = ep[p + 2], e3 = ep[p + 3];
    EP e4 = ep[p + 4], e5 = ep[p + 5], e6 = ep[p + 6], e7 = ep[p + 7];
    a0 = fmaf(X[(size_t)e0.s * 64 + lane], e0.w, a0);
    a1 = fmaf(X[(size_t)e1.s * 64 + lane], e1.w, a1);
    a0 = fmaf(X[(size_t)e2.s * 64 + lane], e2.w, a0);
    a1 = fmaf(X[(size_t)e3.s * 64 + lane], e3.w, a1);
    a0 = fmaf(X[(size_t)e4.s * 64 + lane], e4.w, a0);
    a1 = fmaf(X[(size_t)e5.s * 64 + lane], e5.w, a1);
    a0 = fmaf(X[(size_t)e6.s * 64 + lane], e6.w, a0);
    a1 = fmaf(X[(size_t)e7.s * 64 + lane], e7.w, a1);
  }
  for (; p < p1; ++p) { EP e = ep[p]; a0 = fmaf(X[(size_t)e.s * 64 + lane], e.w, a0); }
  return a0 + a1;
}

// CSR gather + deg-norm + (agg@W + b) + optional score/raw.
// GEMM via wave-local LDS broadcast row (smrow = this wave's private 64 floats).
static __device__ __forceinline__ void rowaggD(
    const float* __restrict__ X, const EP* __restrict__ ep,
    const int* __restrict__ rp, float rsdv,
    const float* __restrict__ W, const float* __restrict__ b,
    float* __restrict__ outp, int row, int lane, float* __restrict__ smrow,
    const float* fcW, const float* fcb, const float* av, float* score,
    float* __restrict__ rawAgg) {
  float acc = gatherEP(ep, rp[row], rp[row + 1], X, lane);
  if (rawAgg) rawAgg[(size_t)row * 64 + lane] = acc;
  smrow[lane] = acc * rsdv;
  float m = b[lane];
#pragma unroll 8
  for (int k = 0; k < 64; ++k) m = fmaf(smrow[k], W[k * 64 + lane], m);
  outp[(size_t)row * 64 + lane] = m;
  if (score) {
    smrow[lane] = m;
    float fa = fcb[lane];
#pragma unroll 8
    for (int k = 0; k < 64; ++k) fa = fmaf(smrow[k], fcW[k * 64 + lane], fa);
    float part = waveSum(tanhf(fa) * av[lane]);
    if (lane == 0) atomicAdd(&score[(blockIdx.x & 63) * 16], part);
  }
}

// degree histograms (6 arrays) + input projections, fused
__global__ __launch_bounds__(256) void k_histproj(
    const int* __restrict__ sr0, const int* __restrict__ ds0,
    const int* __restrict__ sr1, const int* __restrict__ ds1,
    const int* __restrict__ sr2, const int* __restrict__ ds2,
    int* __restrict__ cnt,
    const float* __restrict__ features, const float* __restrict__ feato,
    const float* __restrict__ Wt, const float* __restrict__ bt,
    const float* __restrict__ Wo, const float* __restrict__ bo,
    float* __restrict__ Tx0t, float* __restrict__ Tx0o) {
  int gtid = blockIdx.x * 256 + threadIdx.x;
  int TOT = gridDim.x * 256;
  for (int i = gtid; i < E0C; i += TOT) {
    atomicAdd(&cnt[OCD0 + ds0[i]], 1);
    atomicAdd(&cnt[OCS0 + sr0[i]], 1);
  }
  for (int i = gtid; i < E1C; i += TOT) {
    atomicAdd(&cnt[OCD1 + ds1[i]], 1);
    atomicAdd(&cnt[OCS1 + sr1[i]], 1);
  }
  for (int i = gtid; i < E2C; i += TOT) {
    atomicAdd(&cnt[OCD2 + ds2[i]], 1);
    atomicAdd(&cnt[OCS2 + sr2[i]], 1);
  }
  int lane = threadIdx.x & 63;
  int gw = gtid >> 6, NW = TOT >> 6;
  for (int r = gw; r < NT + NO; r += NW) {
    if (r < NT) {
      const float* x = features + (size_t)r * 334;
      float a = bt[lane];
      for (int k = 0; k < 334; ++k) a = fmaf(x[k], Wt[k * 64 + lane], a);
      Tx0t[(size_t)r * 64 + lane] = a;
    } else {
      int ro = r - NT;
      const float* x = feato + (size_t)ro * 128;
      float a = bo[lane];
      for (int k = 0; k < 128; ++k) a = fmaf(x[k], Wo[k * 64 + lane], a);
      Tx0o[(size_t)ro * 64 + lane] = a;
    }
  }
}

// rs = 1/sqrt(max(cnt,1)); chunk-local exclusive scans (48 blocks)
__global__ __launch_bounds__(1024) void k_rsScan(
    const int* __restrict__ cnt, float* __restrict__ rs,
    int* __restrict__ rp0, int* __restrict__ rp1, int* __restrict__ rp2,
    int* __restrict__ ctot) {
  __shared__ int wsums[16];
  int tid = threadIdx.x, lane = tid & 63, wid = tid >> 6;
  for (int i = blockIdx.x * 1024 + tid; i < 96000; i += 48 * 1024)
    rs[i] = 1.0f / sqrtf(fmaxf((float)cnt[i], 1.0f));
  int ct = blockIdx.x;
  int rel, chunk;
  if (ct < 12) { rel = 0; chunk = ct; }
  else if (ct < 36) { rel = 1; chunk = ct - 12; }
  else { rel = 2; chunk = ct - 36; }
  int n = (rel == 1) ? NO : NT;
  const int* cdp = cnt + ((rel == 0) ? OCD0 : (rel == 1) ? OCD1 : OCD2);
  int* rpp = (rel == 0) ? rp0 : (rel == 1) ? rp1 : rp2;
  int i = chunk * 1024 + tid;
  int vI = (i < n) ? cdp[i] : 0;
  int s = vI;
#pragma unroll
  for (int d = 1; d < 64; d <<= 1) { int t = __shfl_up(s, d, 64); if (lane >= d) s += t; }
  if (lane == 63) wsums[wid] = s;
  __syncthreads();
  if (tid < 16) {
    int w = wsums[tid];
#pragma unroll
    for (int d = 1; d < 16; d <<= 1) { int t = __shfl_up(w, d, 64); if (tid >= d) w += t; }
    wsums[tid] = w;
  }
  __syncthreads();
  int wbase = wid ? wsums[wid - 1] : 0;
  if (i < n) rpp[i] = wbase + s - vI;
  if (tid == 0) ctot[rel * 40 + chunk] = wsums[15];
}

// chunk-base fix (block-local 48-entry prefix)
__global__ __launch_bounds__(256) void k_rpfix(
    int* __restrict__ rp0, int* __restrict__ rp1, int* __restrict__ rp2,
    const int* __restrict__ ctot) {
  __shared__ int cb[120];
  if (threadIdx.x == 0) {
    int b = 0;
    for (int c = 0; c < 12; ++c) { cb[c] = b; b += ctot[c]; }
    if (blockIdx.x == 0) rp0[NT] = b;
    b = 0;
    for (int c = 0; c < 24; ++c) { cb[40 + c] = b; b += ctot[40 + c]; }
    if (blockIdx.x == 0) rp1[NO] = b;
    b = 0;
    for (int c = 0; c < 12; ++c) { cb[80 + c] = b; b += ctot[80 + c]; }
    if (blockIdx.x == 0) rp2[NT] = b;
  }
  __syncthreads();
  int i = blockIdx.x * 256 + threadIdx.x;
  int TOT = gridDim.x * 256;
  for (int j = i; j < NT; j += TOT) rp0[j] += cb[j >> 10];
  for (int j = i; j < NO; j += TOT) rp1[j] += cb[40 + (j >> 10)];
  for (int j = i; j < NT; j += TOT) rp2[j] += cb[80 + (j >> 10)];
}

__global__ void k_fill(
    const int* __restrict__ sr0, const int* __restrict__ ds0,
    const int* __restrict__ sr1, const int* __restrict__ ds1,
    const int* __restrict__ sr2, const int* __restrict__ ds2,
    const int* __restrict__ rp0, const int* __restrict__ rp1,
    const int* __restrict__ rp2, int* __restrict__ fil,
    const float* __restrict__ rs,
    EP* __restrict__ ep0, EP* __restrict__ ep1, EP* __restrict__ ep2) {
  int gtid = blockIdx.x * 256 + threadIdx.x;
  int TOT = gridDim.x * 256;
  for (int e = gtid; e < E0C; e += TOT) {
    int d = ds0[e];
    int pos = rp0[d] + atomicAdd(&fil[d], 1);
    EP pk; pk.s = sr0[e]; pk.w = rs[OCS0 + pk.s];
    ep0[pos] = pk;
  }
  for (int e = gtid; e < E1C; e += TOT) {
    int d = ds1[e];
    int pos = rp1[d] + atomicAdd(&fil[12000 + d], 1);
    EP pk; pk.s = sr1[e]; pk.w = rs[OCS1 + pk.s];
    ep1[pos] = pk;
  }
  for (int e = gtid; e < E2C; e += TOT) {
    int d = ds2[e];
    int pos = rp2[d] + atomicAdd(&fil[36000 + d], 1);
    EP pk; pk.s = sr2[e]; pk.w = rs[OCS2 + pk.s];
    ep2[pos] = pk;
  }
}

// layer-1: all 3 relation GraphConvs; r2 branch also saves raw agg = A_0
// NT % 4 == 0 => every 4-wave block is branch-homogeneous.
__global__ __launch_bounds__(256) void k_layer1(
    const float* __restrict__ Tx0t, const float* __restrict__ Tx0o,
    const float* __restrict__ rs,
    const int* __restrict__ rp0, const EP* __restrict__ ep0,
    const int* __restrict__ rp1, const EP* __restrict__ ep1,
    const int* __restrict__ rp2, const EP* __restrict__ ep2,
    const float* __restrict__ W1r0, const float* __restrict__ b1r0,
    const float* __restrict__ W1r1, const float* __restrict__ b1r1,
    const float* __restrict__ W1r2, const float* __restrict__ b1r2,
    const float* __restrict__ a1W, const float* __restrict__ a1b,
    const float* __restrict__ a1v,
    float* __restrict__ mt0L, float* __restrict__ m2A, float* __restrict__ Tx1o,
    float* __restrict__ aggB0, float* __restrict__ sc) {
  __shared__ float sm[4][64];
  int wid = threadIdx.x >> 6, lane = threadIdx.x & 63;
  int t = blockIdx.x * 4 + wid;
  if (t < NT) {
    rowaggD(Tx0o, ep0, rp0, rs[OCD0 + t], W1r0, b1r0, mt0L, t, lane, sm[wid],
            a1W, a1b, a1v, sc + 0 * SCSTRIDE, nullptr);
  } else if (t < 2 * NT) {
    int r = t - NT;
    rowaggD(Tx0t, ep2, rp2, rs[OCD2 + r], W1r2, b1r2, m2A, r, lane, sm[wid],
            a1W, a1b, a1v, sc + 1 * SCSTRIDE, aggB0);  // raw = G(S_0) = A_0
  } else {
    int r = t - 2 * NT;
    rowaggD(Tx0t, ep1, rp1, rs[OCD1 + r], W1r1, b1r1, Tx1o, r, lane, sm[wid],
            nullptr, nullptr, nullptr, nullptr, nullptr);
  }
}

// layer-1 combine + GPR heads 0,1 fused with invariant mt0b rowagg
__global__ __launch_bounds__(256) void k_comb1(
    const float* __restrict__ Tx0t, const float* __restrict__ mt0L,
    const float* __restrict__ m2A, const float* __restrict__ Tx1o,
    const float* __restrict__ rs,
    const int* __restrict__ rp0, const EP* __restrict__ ep0,
    const float* __restrict__ W2r0, const float* __restrict__ b2r0,
    const float* __restrict__ a2W, const float* __restrict__ a2b,
    const float* __restrict__ a2v,
    const float* __restrict__ projW, const float* __restrict__ projb,
    const float* __restrict__ gamma,
    float* __restrict__ Tx1t, float* __restrict__ hidden, float* __restrict__ mt0b,
    float* __restrict__ sc) {
  __shared__ float smA[4][64];
  __shared__ float smB[4][64];
  int wid = threadIdx.x >> 6, lane = threadIdx.x & 63;
  int t = blockIdx.x * 4 + wid;
  if (t < NT) {
    int r = t;
    size_t o = (size_t)r * 64 + lane;
    float t0 = Tx0t[o];
    float m0v = mt0L[o];
    float m2v = m2A[o];
    float s0 = scSum(sc, 0, lane) * INV_NT;
    float s1 = scSum(sc, 1, lane) * INV_NT;
    float mx = fmaxf(s0, s1);
    float e0 = expf(s0 - mx), e1 = expf(s1 - mx);
    float inv = 1.0f / (e0 + e1);
    float t1v = e0 * inv * m0v + e1 * inv * m2v;
    Tx1t[o] = t1v;
    smA[wid][lane] = t0;
    smB[wid][lane] = t1v;
    int half = lane >> 5, hl = lane & 31;
    const float* pw = projW + (size_t)half * 2048;
    const float* src = half ? smB[wid] : smA[wid];
    float pa = projb[half * 32 + hl];
#pragma unroll 8
    for (int k = 0; k < 64; ++k)
      pa = fmaf(src[k], pw[k * 32 + hl], pa);
    float part = tanhf(pa) * gamma[hl * (KORD + 1) + half];
#pragma unroll
    for (int d = 16; d >= 1; d >>= 1) part += __shfl_xor(part, d, 64);
    float eta0 = __shfl(part, 0, 64) * (1.0f / 32.0f);
    float eta1 = __shfl(part, 32, 64) * (1.0f / 32.0f);
    hidden[o] = t0 * eta0 + t1v * eta1;
  } else {
    int r = t - NT;
    rowaggD(Tx1o, ep0, rp0, rs[OCD0 + r], W2r0, b2r0, mt0b, r, lane, smA[wid],
            a2W, a2b, a2v, sc + 2 * SCSTRIDE, nullptr);
  }
}

// j=1: blocks<3000 gather S_1 -> A_1 raw + mt2_1 + score slot 3;
// blocks>=3000: invariant g0 = G(mt0b).
__global__ __launch_bounds__(256) void k_iter1(
    const float* __restrict__ Tx1t, const float* __restrict__ mt0b,
    const float* __restrict__ rsd2, const int* __restrict__ rp2,
    const EP* __restrict__ ep2,
    const float* __restrict__ W, const float* __restrict__ bW,
    const float* __restrict__ fcW, const float* __restrict__ fcb,
    const float* __restrict__ av,
    float* __restrict__ mtdst, float* __restrict__ aggB1,
    float* __restrict__ g0, float* __restrict__ scoreNew) {
  __shared__ float sm[4][64];
  int wid = threadIdx.x >> 6, lane = threadIdx.x & 63;
  if (blockIdx.x < 3000) {
    int row = blockIdx.x * 4 + wid;
    rowaggD(Tx1t, ep2, rp2, rsd2[row], W, bW, mtdst, row, lane, sm[wid],
            fcW, fcb, av, scoreNew, aggB1);
  } else {
    int r = blockIdx.x * 4 + wid - NT;
    g0[(size_t)r * 64 + lane] = gatherEP(ep2, rp2[r], rp2[r + 1], mt0b, lane);
  }
}

// Fused GPR iteration j>=2 (ONE dispatch); LDS-broadcast GEMMs
__global__ __launch_bounds__(256) void k_iterF(
    const float* __restrict__ mt2prev, const float* __restrict__ g0,
    float* __restrict__ agg,  // read A_{j-2}, write A_j (same element, same thread)
    const float* __restrict__ mt0b, const float* __restrict__ Tsrc2,
    float* __restrict__ Tdst,
    const float* __restrict__ rsd2, const int* __restrict__ rp2,
    const EP* __restrict__ ep2,
    const float* __restrict__ W, const float* __restrict__ bW,
    const float* __restrict__ fcW, const float* __restrict__ fcb,
    const float* __restrict__ av,
    const float* __restrict__ sc, int slotPrev, float* __restrict__ scoreNew,
    const float* __restrict__ projW, const float* __restrict__ projb,
    const float* __restrict__ gamma, int kidx,
    float* __restrict__ hidden, float* __restrict__ mtdst) {
  __shared__ float sm[4][64];
  int wid = threadIdx.x >> 6, lane = threadIdx.x & 63;
  float* smrow = sm[wid];
  int r = blockIdx.x * 4 + wid;
  float s0 = scSum(sc, 2, lane) * INV_NT;
  float s1 = scSum(sc, slotPrev, lane) * INV_NT;
  float mx = fmaxf(s0, s1);
  float e0 = expf(s0 - mx), e1 = expf(s1 - mx);
  float inv = 1.0f / (e0 + e1);
  float tw0 = 2.0f * e0 * inv, tw1 = 2.0f * e1 * inv;
  float gm = gatherEP(ep2, rp2[r], rp2[r + 1], mt2prev, lane);
  size_t o = (size_t)r * 64 + lane;
  float aggj = fmaf(tw0, g0[o], fmaf(tw1, gm, -agg[o]));
  agg[o] = aggj;
  smrow[lane] = aggj * rsd2[r];
  float m = bW[lane];
#pragma unroll 8
  for (int k = 0; k < 64; ++k) m = fmaf(smrow[k], W[k * 64 + lane], m);
  mtdst[o] = m;
  smrow[lane] = m;
  float fa = fcb[lane];
#pragma unroll 8
  for (int k = 0; k < 64; ++k) fa = fmaf(smrow[k], fcW[k * 64 + lane], fa);
  float part = waveSum(tanhf(fa) * av[lane]);
  if (lane == 0) atomicAdd(&scoreNew[(blockIdx.x & 63) * 16], part);
  float tj = fmaf(tw0, mt0b[o], fmaf(tw1, mt2prev[o], -Tsrc2[o]));
  Tdst[o] = tj;
  smrow[lane] = tj;
  float eta = gprEta(smrow, projW, projb, gamma, kidx, lane);
  hidden[o] += tj * eta;
}

// T10 fold + h=tanh -> out, logits, loss partial, stage-1 MLP for h and z_p
__global__ __launch_bounds__(256) void k_post1(
    float* __restrict__ hidden, const float* __restrict__ mt0b,
    const float* __restrict__ mt9, const float* __restrict__ T8,
    const float* __restrict__ sc,
    const float* __restrict__ projW, const float* __restrict__ projb,
    const float* __restrict__ gamma,
    const float* __restrict__ z_pre,
    const float* __restrict__ p3W, const float* __restrict__ p3b,
    const float* __restrict__ outW, const float* __restrict__ outb,
    const float* __restrict__ p1W1, const float* __restrict__ p1b1,
    float* __restrict__ outH, float* __restrict__ outLogits,
    float* __restrict__ t1, float* __restrict__ t1z,
    float* __restrict__ lossAcc) {
  __shared__ float smH[4][64];
  __shared__ float smZ[4][64];
  int wid = threadIdx.x >> 6, lane = threadIdx.x & 63;
  int row = blockIdx.x * 4 + wid;
  size_t o = (size_t)row * 64 + lane;
  float s0 = scSum(sc, 2, lane) * INV_NT;
  float s1 = scSum(sc, 11, lane) * INV_NT;
  float mx = fmaxf(s0, s1);
  float e0 = expf(s0 - mx), e1 = expf(s1 - mx);
  float inv = 1.0f / (e0 + e1);
  float tw0 = 2.0f * e0 * inv, tw1 = 2.0f * e1 * inv;
  float t10 = fmaf(tw0, mt0b[o], fmaf(tw1, mt9[o], -T8[o]));
  smH[wid][lane] = t10;
  float eta = gprEta(smH[wid], projW, projb, gamma, KORD, lane);
  float hfin = hidden[o] + t10 * eta;
  hidden[o] = hfin;  // adj reads this
  float hv = tanhf(hfin);
  outH[o] = hv;
  const float* zr = z_pre + (size_t)row * 128;
  float zpv = p3b[lane];
  for (int k = 0; k < 128; ++k) zpv = fmaf(zr[k], p3W[k * 64 + lane], zpv);
  smH[wid][lane] = hv;
  smZ[wid][lane] = zpv;
  float hm = waveSum(hv) * (1.0f / 64.0f);
  float zm = waveSum(zpv) * (1.0f / 64.0f);
  float cv = waveSum((hv - hm) * (zpv - zm)) * (1.0f / 64.0f);
  if (lane == 0) atomicAdd(&lossAcc[(blockIdx.x & 63) * 16], cv);
#pragma unroll
  for (int j = 0; j < 3; ++j) {
    float pj = waveSum(hv * outW[lane * 3 + j]);
    if (lane == 0) outLogits[row * 3 + j] = pj + outb[j];
  }
  float a0 = p1b1[lane], a1 = p1b1[64 + lane];
  float z0 = a0, z1 = a1;
#pragma unroll 4
  for (int k = 0; k < 64; ++k) {
    float hk = smH[wid][k];
    float zk = smZ[wid][k];
    float wlo = p1W1[k * 128 + lane], whi = p1W1[k * 128 + 64 + lane];
    a0 = fmaf(hk, wlo, a0); a1 = fmaf(hk, whi, a1);
    z0 = fmaf(zk, wlo, z0); z1 = fmaf(zk, whi, z1);
  }
  t1[(size_t)row * 128 + lane] = fmaxf(a0, 0.f);
  t1[(size_t)row * 128 + 64 + lane] = fmaxf(a1, 0.f);
  t1z[(size_t)row * 128 + lane] = fmaxf(z0, 0.f);
  t1z[(size_t)row * 128 + 64 + lane] = fmaxf(z1, 0.f);
}

// Fused: blocks [0,NADJ) = C=H@H^T triangular tiles (16-deep k phases, plain
// stores through L2); blocks >= NADJ = stage-2 MLP + loss finalize.
__global__ __launch_bounds__(256) void k_adjpost(
    const float* __restrict__ H, float* __restrict__ C, int N,
    const float* __restrict__ t1, const float* __restrict__ t1z,
    const float* __restrict__ p1W2, const float* __restrict__ p1b2,
    float* __restrict__ xpre, float* __restrict__ zpre1,
    const float* __restrict__ lossAcc, float* __restrict__ outLoss) {
  __shared__ float sh[4224];  // As = sh[0..2111] (16x132), Bs = sh[2112..4223]
  int b = blockIdx.x;
  if (b < NADJ) {
    int bi = 0, idx = b, rowlen = NB;
    while (idx >= rowlen) { idx -= rowlen; --rowlen; ++bi; }
    int bj = bi + idx;
    int tid = threadIdx.x;
    int tx = tid & 15, ty = tid >> 4;
    int rb = tid & 127, halfq = tid >> 7;  // load indexing
    float acc[8][8] = {};
    for (int kt = 0; kt < 64; kt += 16) {
      {
        int gi = bi * 128 + rb;
        int gj = bj * 128 + rb;
#pragma unroll
        for (int l = 0; l < 2; ++l) {
          int kk = (halfq * 2 + l) * 4;
          float4 a = (gi < N) ? *reinterpret_cast<const float4*>(&H[(size_t)gi * 64 + kt + kk])
                              : make_float4(0.f, 0.f, 0.f, 0.f);
          sh[(kk + 0) * 132 + rb] = a.x; sh[(kk + 1) * 132 + rb] = a.y;
          sh[(kk + 2) * 132 + rb] = a.z; sh[(kk + 3) * 132 + rb] = a.w;
          float4 bb = (gj < N) ? *reinterpret_cast<const float4*>(&H[(size_t)gj * 64 + kt + kk])
                               : make_float4(0.f, 0.f, 0.f, 0.f);
          sh[2112 + (kk + 0) * 132 + rb] = bb.x; sh[2112 + (kk + 1) * 132 + rb] = bb.y;
          sh[2112 + (kk + 2) * 132 + rb] = bb.z; sh[2112 + (kk + 3) * 132 + rb] = bb.w;
        }
      }
      __syncthreads();
#pragma unroll 8
      for (int k = 0; k < 16; ++k) {
        float4 a0 = *reinterpret_cast<const float4*>(&sh[k * 132 + ty * 4]);
        float4 a1 = *reinterpret_cast<const float4*>(&sh[k * 132 + 64 + ty * 4]);
        float4 b0 = *reinterpret_cast<const float4*>(&sh[2112 + k * 132 + tx * 4]);
        float4 b1 = *reinterpret_cast<const float4*>(&sh[2112 + k * 132 + 64 + tx * 4]);
        float av[8] = {a0.x, a0.y, a0.z, a0.w, a1.x, a1.y, a1.z, a1.w};
        float bv[8] = {b0.x, b0.y, b0.z, b0.w, b1.x, b1.y, b1.z, b1.w};
#pragma unroll
        for (int i = 0; i < 8; ++i)
#pragma unroll
          for (int j = 0; j < 8; ++j) acc[i][j] = fmaf(av[i], bv[j], acc[i][j]);
      }
      __syncthreads();
    }
#pragma unroll
    for (int g = 0; g < 2; ++g) {
#pragma unroll
      for (int i = 0; i < 4; ++i) {
        int gr = bi * 128 + g * 64 + ty * 4 + i;
        if (gr >= N) continue;
#pragma unroll
        for (int h = 0; h < 2; ++h) {
          int gc = bj * 128 + h * 64 + tx * 4;
          if (gc >= N) continue;
          nfloat4 vv = {acc[g * 4 + i][h * 4 + 0], acc[g * 4 + i][h * 4 + 1],
                        acc[g * 4 + i][h * 4 + 2], acc[g * 4 + i][h * 4 + 3]};
          *reinterpret_cast<nfloat4*>(&C[(size_t)gr * N + gc]) = vv;
        }
      }
    }
    if (bi != bj) {
      float* T = sh;
      int cc = tid >> 4, f4 = tid & 15;
#pragma unroll
      for (int g = 0; g < 2; ++g) {
#pragma unroll
        for (int h = 0; h < 2; ++h) {
          __syncthreads();
#pragma unroll
          for (int i = 0; i < 4; ++i) {
            int r = ty * 4 + i;
#pragma unroll
            for (int j = 0; j < 4; ++j)
              T[r * 65 + tx * 4 + j] = acc[g * 4 + i][h * 4 + j];
          }
          __syncthreads();
          int gr0 = bi * 128 + g * 64 + f4 * 4;
#pragma unroll
          for (int c0 = 0; c0 < 64; c0 += 16) {
            int c = c0 + cc;
            int gc = bj * 128 + h * 64 + c;
            if (gc < N) {
              nfloat4 v = {T[(f4 * 4 + 0) * 65 + c], T[(f4 * 4 + 1) * 65 + c],
                           T[(f4 * 4 + 2) * 65 + c], T[(f4 * 4 + 3) * 65 + c]};
              *reinterpret_cast<nfloat4*>(&C[(size_t)gc * N + gr0]) = v;
            }
          }
        }
      }
    }
    return;
  }
  // ---- post2 part ----
  int qb = b - NADJ;  // 0..1499
  if (qb == 0 && threadIdx.x < 64) {
    float v = waveSum(lossAcc[threadIdx.x * 16]);
    if (threadIdx.x == 0) {
      float s = v * (1.0f / NT);
      outLoss[0] = s * s;  // loss_dis1 (1-row HSIC) is exactly 0
    }
  }
  int wid = threadIdx.x >> 6, lane = threadIdx.x & 63;
  int q = qb * 4 + wid;  // 0..5999
  bool isz = q >= 3000;
  int r0 = (isz ? q - 3000 : q) * 4;
  const float* T = isz ? t1z : t1;
  float* D = isz ? zpre1 : xpre;
  float lo[4], hi[4];
#pragma unroll
  for (int rr = 0; rr < 4; ++rr) {
    lo[rr] = T[(size_t)(r0 + rr) * 128 + lane];
    hi[rr] = T[(size_t)(r0 + rr) * 128 + 64 + lane];
  }
  for (int c0 = 0; c0 < 384; c0 += 64) {
    int c = c0 + lane;
    bool ok = c < 334;
    float bb = ok ? p1b2[c] : 0.f;
    float acc0 = bb, acc1 = bb, acc2 = bb, acc3 = bb;
    for (int k = 0; k < 64; ++k) {
      float w = ok ? p1W2[k * 334 + c] : 0.f;
      acc0 = fmaf(__shfl(lo[0], k, 64), w, acc0);
      acc1 = fmaf(__shfl(lo[1], k, 64), w, acc1);
      acc2 = fmaf(__shfl(lo[2], k, 64), w, acc2);
      acc3 = fmaf(__shfl(lo[3], k, 64), w, acc3);
    }
    for (int k = 0; k < 64; ++k) {
      float w = ok ? p1W2[(64 + k) * 334 + c] : 0.f;
      acc0 = fmaf(__shfl(hi[0], k, 64), w, acc0);
      acc1 = fmaf(__shfl(hi[1], k, 64), w, acc1);
      acc2 = fmaf(__shfl(hi[2], k, 64), w, acc2);
      acc3 = fmaf(__shfl(hi[3], k, 64), w, acc3);
    }
    if (ok) {
      D[(size_t)(r0 + 0) * 334 + c] = tanhf(acc0);
      D[(size_t)(r0 + 1) * 334 + c] = tanhf(acc1);
      D[(size_t)(r0 + 2) * 334 + c] = tanhf(acc2);
      D[(size_t)(r0 + 3) * 334 + c] = tanhf(acc3);
    }
  }
}

extern "C" void kernel_launch(void* const* d_in, const int* in_sizes, int n_in,
                              void* d_out, int out_size, void* d_ws, size_t ws_size,
                              hipStream_t stream) {
  const float* features_v1 = (const float*)d_in[0];
  const float* feat_other = (const float*)d_in[1];
  const float* z_pre = (const float*)d_in[2];
  const float* Wt = (const float*)d_in[3];  const float* bt = (const float*)d_in[4];
  const float* Wo = (const float*)d_in[5];  const float* bo = (const float*)d_in[6];
  const float* W1r0 = (const float*)d_in[7];  const float* b1r0 = (const float*)d_in[8];
  const float* W1r1 = (const float*)d_in[9];  const float* b1r1 = (const float*)d_in[10];
  const float* W1r2 = (const float*)d_in[11]; const float* b1r2 = (const float*)d_in[12];
  const float* a1W = (const float*)d_in[13]; const float* a1b = (const float*)d_in[14];
  const float* a1v = (const float*)d_in[15];
  const float* W2r0 = (const float*)d_in[16]; const float* b2r0 = (const float*)d_in[17];
  // d_in[18]/d_in[19] (W2r1/b2r1) feed only the discarded loop out_o — unused.
  const float* W2r2 = (const float*)d_in[20]; const float* b2r2 = (const float*)d_in[21];
  const float* a2W = (const float*)d_in[22]; const float* a2b = (const float*)d_in[23];
  const float* a2v = (const float*)d_in[24];
  const float* projW = (const float*)d_in[25]; const float* projb = (const float*)d_in[26];
  const float* gamma = (const float*)d_in[27];
  const float* p3W = (const float*)d_in[28]; const float* p3b = (const float*)d_in[29];
  const float* p1W1 = (const float*)d_in[30]; const float* p1b1 = (const float*)d_in[31];
  const float* p1W2 = (const float*)d_in[32]; const float* p1b2 = (const float*)d_in[33];
  const float* outW = (const float*)d_in[34]; const float* outb = (const float*)d_in[35];
  const int* sr0 = (const int*)d_in[36]; const int* ds0 = (const int*)d_in[37];
  const int* sr1 = (const int*)d_in[38]; const int* ds1 = (const int*)d_in[39];
  const int* sr2 = (const int*)d_in[40]; const int* ds2 = (const int*)d_in[41];

  float* out = (float*)d_out;
  const size_t LOGITS_OFF = 0;
  const size_t H_OFF = (size_t)NT * 3;
  const size_t XPRE_OFF = H_OFF + (size_t)NT * 64;
  const size_t ZPRE_OFF = XPRE_OFF + (size_t)NT * 334;
  const size_t ADJ_OFF = ZPRE_OFF + (size_t)NT * 334;
  const size_t LOSS_OFF = ADJ_OFF + (size_t)NT * NT;

  float* ws = (float*)d_ws;
  size_t o = 0;
  auto alloc = [&](size_t n) { float* p = ws + o; o += n; return p; };
  float* Tbuf0 = alloc((size_t)NT * 64);   // S_0 (= Tx0t)
  float* Tbuf1 = alloc((size_t)NT * 64);   // S_1
  float* Tbuf2 = alloc((size_t)NT * 64);
  float* Tx0o = alloc((size_t)NO * 64);
  float* Tx1o = alloc((size_t)NO * 64);
  float* mt0L = alloc((size_t)NT * 64);
  float* mt0b = alloc((size_t)NT * 64);
  float* m2A  = alloc((size_t)NT * 64);
  float* m2B  = alloc((size_t)NT * 64);
  float* hidden = alloc((size_t)NT * 64);
  float* t1   = alloc((size_t)NT * 128);
  float* t1z  = alloc((size_t)NT * 128);
  float* g0   = alloc((size_t)NT * 64);   // G(mt0b), loop-invariant
  float* aggB0 = alloc((size_t)NT * 64);  // A_{even}
  float* aggB1 = alloc((size_t)NT * 64);  // A_{odd}
  float* rs   = alloc(96000);
  // score slots 0..11 (1024 floats each, 64 buckets x 16 stride), loss = slot 12
  float* sc   = alloc(13 * SCSTRIDE);  // memset region starts here
  int* cnt = (int*)(ws + o); o += 96000;
  int* fil = (int*)(ws + o); o += 48000;
  int* rp0 = (int*)(ws + o); o += NT + 1;
  int* rp1 = (int*)(ws + o); o += NO + 1;
  int* rp2 = (int*)(ws + o); o += NT + 1;
  int* ctot = (int*)(ws + o); o += 120;
  o = (o + 1) & ~(size_t)1;  // 8-byte align for EP arrays
  EP* ep0 = (EP*)(ws + o); o += (size_t)E0C * 2;
  EP* ep1 = (EP*)(ws + o); o += (size_t)E1C * 2;
  EP* ep2 = (EP*)(ws + o); o += (size_t)E2C * 2;

  // zero accumulators: sc(13*1024) + cnt(96000) + fil(48000), contiguous
  (void)hipMemsetAsync(sc, 0, (13 * SCSTRIDE + 96000 + 48000) * sizeof(float), stream);

  k_histproj<<<2048, 256, 0, stream>>>(sr0, ds0, sr1, ds1, sr2, ds2, cnt,
                                       features_v1, feat_other, Wt, bt, Wo, bo,
                                       Tbuf0, Tx0o);
  k_rsScan<<<48, 1024, 0, stream>>>(cnt, rs, rp0, rp1, rp2, ctot);
  k_rpfix<<<256, 256, 0, stream>>>(rp0, rp1, rp2, ctot);
  k_fill<<<2048, 256, 0, stream>>>(sr0, ds0, sr1, ds1, sr2, ds2, rp0, rp1, rp2,
                                   fil, rs, ep0, ep1, ep2);
  k_layer1<<<12000, 256, 0, stream>>>(Tbuf0, Tx0o, rs,
                                      rp0, ep0, rp1, ep1, rp2, ep2,
                                      W1r0, b1r0, W1r1, b1r1, W1r2, b1r2,
                                      a1W, a1b, a1v, mt0L, m2A, Tx1o, aggB0, sc);
  k_comb1<<<6000, 256, 0, stream>>>(Tbuf0, mt0L, m2A, Tx1o, rs, rp0, ep0,
                                    W2r0, b2r0, a2W, a2b, a2v,
                                    projW, projb, gamma,
                                    Tbuf1, hidden, mt0b, sc);

  float* Tb[3] = {Tbuf0, Tbuf1, Tbuf2};
  float* Mb[2] = {m2A, m2B};
  float* Ab[2] = {aggB0, aggB1};
  const float* rsd2 = rs + OCD2;
  // j=1: gather S_1 -> A_1 + mt2_1 (Mb[1]) + score slot 3; also g0 = G(mt0b)
  k_iter1<<<6000, 256, 0, stream>>>(Tbuf1, mt0b, rsd2, rp2, ep2,
                                    W2r2, b2r2, a2W, a2b, a2v,
                                    Mb[1], aggB1, g0, sc + 3 * SCSTRIDE);
  for (int j = 2; j <= 9; ++j) {
    k_iterF<<<3000, 256, 0, stream>>>(Mb[(j - 1) & 1], g0, Ab[j & 1],
                                      mt0b, Tb[(j - 2) % 3], Tb[j % 3],
                                      rsd2, rp2, ep2, W2r2, b2r2,
                                      a2W, a2b, a2v, sc, 2 + j - 1,
                                      sc + (2 + j) * SCSTRIDE,
                                      projW, projb, gamma, j,
                                      hidden, Mb[j & 1]);
  }
  // S_9 in Tb[0]; S_8 in Tb[2]; mt2_9 in Mb[1]

  k_post1<<<3000, 256, 0, stream>>>(hidden, mt0b, Mb[1], Tb[2], sc,
                                    projW, projb, gamma, z_pre, p3W, p3b,
                                    outW, outb, p1W1, p1b1,
                                    out + H_OFF, out + LOGITS_OFF, t1, t1z,
                                    sc + 12 * SCSTRIDE);
  k_adjpost<<<NADJ + 1500, 256, 0, stream>>>(hidden, out + ADJ_OFF, NT,
                                             t1, t1z, p1W2, p1b2,
                                             out + XPRE_OFF, out + ZPRE_OFF,
                                             sc + 12 * SCSTRIDE, out + LOSS_OFF);
}

// Round 13
// 980.140 us; speedup vs baseline: 1.7892x; 1.1290x over previous
//
#include <hip/hip_runtime.h>
#include <math.h>

#define NT 12000
#define NO 24000
#define KORD 10
#define E0C 384000
#define E1C 384000
#define E2C 192000
#define INV_NT (1.0f / 12000.0f)
#define NB 94              // ceil(12000/128) adj tiles
#define NADJ ((NB * (NB + 1)) / 2)  // 4465 triangular blocks
#define SCSTRIDE 1024      // one score slot = 64 buckets x 16-float stride

typedef float nfloat4 __attribute__((ext_vector_type(4)));

struct __align__(8) EP { int s; float w; };  // packed edge: src index + weight

// rs/cnt layout offsets: [cd0 NT][cd1 NO][cd2 NT][cs0 NO][cs1 NT][cs2 NT]
#define OCD0 0
#define OCD1 12000
#define OCD2 36000
#define OCS0 48000
#define OCS1 72000
#define OCS2 84000

static __device__ __forceinline__ float waveSum(float v) {
  v += __shfl_xor(v, 32, 64);
  v += __shfl_xor(v, 16, 64);
  v += __shfl_xor(v, 8, 64);
  v += __shfl_xor(v, 4, 64);
  v += __shfl_xor(v, 2, 64);
  v += __shfl_xor(v, 1, 64);
  return v;
}

// sum of a 64-bucket score slot (bucket i at stride 16 => 1 cache line each)
static __device__ __forceinline__ float scSum(const float* __restrict__ scb,
                                              int slot, int lane) {
  return waveSum(scb[slot * SCSTRIDE + lane * 16]);
}

// eta for proj head kidx; row vector in wave-local LDS row smrow[0..63]
static __device__ __forceinline__ float gprEta(const float* __restrict__ smrow,
                                               const float* __restrict__ pwAll,
                                               const float* __restrict__ pb,
                                               const float* __restrict__ gamma,
                                               int kidx, int lane) {
  int hl = lane & 31;
  const float* pw = pwAll + (size_t)kidx * 2048;
  float pa = pb[kidx * 32 + hl];
#pragma unroll 8
  for (int k = 0; k < 64; ++k)
    pa = fmaf(smrow[k], pw[k * 32 + hl], pa);
  float part = tanhf(pa) * gamma[hl * (KORD + 1) + kidx];
#pragma unroll
  for (int d = 16; d >= 1; d >>= 1) part += __shfl_xor(part, d, 64);
  return __shfl(part, 0, 64) * (1.0f / 32.0f);
}

// dual-acc 8-unroll CSR gather over packed edges
static __device__ __forceinline__ float gatherEP(
    const EP* __restrict__ ep, int p0, int p1,
    const float* __restrict__ X, int lane) {
  float a0 = 0.f, a1 = 0.f;
  int p = p0;
  for (; p + 7 < p1; p += 8) {
    EP e0 = ep[p], e1 = ep[p + 1], e2 = ep[p + 2], e3 = ep[p + 3];
    EP e4 = ep[p + 4], e5 = ep[p + 5], e6 = ep[p + 6], e7 = ep[p + 7];
    a0 = fmaf(X[(size_t)e0.s * 64 + lane], e0.w, a0);
    a1 = fmaf(X[(size_t)e1.s * 64 + lane], e1.w, a1);
    a0 = fmaf(X[(size_t)e2.s * 64 + lane], e2.w, a0);
    a1 = fmaf(X[(size_t)e3.s * 64 + lane], e3.w, a1);
    a0 = fmaf(X[(size_t)e4.s * 64 + lane], e4.w, a0);
    a1 = fmaf(X[(size_t)e5.s * 64 + lane], e5.w, a1);
    a0 = fmaf(X[(size_t)e6.s * 64 + lane], e6.w, a0);
    a1 = fmaf(X[(size_t)e7.s * 64 + lane], e7.w, a1);
  }
  for (; p < p1; ++p) { EP e = ep[p]; a0 = fmaf(X[(size_t)e.s * 64 + lane], e.w, a0); }
  return a0 + a1;
}

// CSR gather + deg-norm + (agg@W + b) + optional score/raw.
// GEMM via wave-local LDS broadcast row (smrow = this wave's private 64 floats).
static __device__ __forceinline__ void rowaggD(
    const float* __restrict__ X, const EP* __restrict__ ep,
    const int* __restrict__ rp, float rsdv,
    const float* __restrict__ W, const float* __restrict__ b,
    float* __restrict__ outp, int row, int lane, float* __restrict__ smrow,
    const float* fcW, const float* fcb, const float* av, float* score,
    float* __restrict__ rawAgg) {
  float acc = gatherEP(ep, rp[row], rp[row + 1], X, lane);
  if (rawAgg) rawAgg[(size_t)row * 64 + lane] = acc;
  smrow[lane] = acc * rsdv;
  float m = b[lane];
#pragma unroll 8
  for (int k = 0; k < 64; ++k) m = fmaf(smrow[k], W[k * 64 + lane], m);
  outp[(size_t)row * 64 + lane] = m;
  if (score) {
    smrow[lane] = m;
    float fa = fcb[lane];
#pragma unroll 8
    for (int k = 0; k < 64; ++k) fa = fmaf(smrow[k], fcW[k * 64 + lane], fa);
    float part = waveSum(tanhf(fa) * av[lane]);
    if (lane == 0) atomicAdd(&score[(blockIdx.x & 63) * 16], part);
  }
}

// degree histograms (6 arrays) + input projections (4-row tiling: 4x W reuse)
__global__ __launch_bounds__(256) void k_histproj(
    const int* __restrict__ sr0, const int* __restrict__ ds0,
    const int* __restrict__ sr1, const int* __restrict__ ds1,
    const int* __restrict__ sr2, const int* __restrict__ ds2,
    int* __restrict__ cnt,
    const float* __restrict__ features, const float* __restrict__ feato,
    const float* __restrict__ Wt, const float* __restrict__ bt,
    const float* __restrict__ Wo, const float* __restrict__ bo,
    float* __restrict__ Tx0t, float* __restrict__ Tx0o) {
  int gtid = blockIdx.x * 256 + threadIdx.x;
  int TOT = gridDim.x * 256;
  for (int i = gtid; i < E0C; i += TOT) {
    atomicAdd(&cnt[OCD0 + ds0[i]], 1);
    atomicAdd(&cnt[OCS0 + sr0[i]], 1);
  }
  for (int i = gtid; i < E1C; i += TOT) {
    atomicAdd(&cnt[OCD1 + ds1[i]], 1);
    atomicAdd(&cnt[OCS1 + sr1[i]], 1);
  }
  for (int i = gtid; i < E2C; i += TOT) {
    atomicAdd(&cnt[OCD2 + ds2[i]], 1);
    atomicAdd(&cnt[OCS2 + sr2[i]], 1);
  }
  int lane = threadIdx.x & 63;
  int gw = gtid >> 6, NW = TOT >> 6;
  // 3000 tasks: 4-row groups of target; 6000 tasks: 4-row groups of other
  for (int q = gw; q < 9000; q += NW) {
    if (q < 3000) {
      int r0 = q * 4;
      const float* x0 = features + (size_t)(r0 + 0) * 334;
      const float* x1 = features + (size_t)(r0 + 1) * 334;
      const float* x2 = features + (size_t)(r0 + 2) * 334;
      const float* x3 = features + (size_t)(r0 + 3) * 334;
      float bv = bt[lane];
      float a0 = bv, a1 = bv, a2 = bv, a3 = bv;
      for (int k = 0; k < 334; ++k) {
        float wv = Wt[k * 64 + lane];
        a0 = fmaf(x0[k], wv, a0);
        a1 = fmaf(x1[k], wv, a1);
        a2 = fmaf(x2[k], wv, a2);
        a3 = fmaf(x3[k], wv, a3);
      }
      Tx0t[(size_t)(r0 + 0) * 64 + lane] = a0;
      Tx0t[(size_t)(r0 + 1) * 64 + lane] = a1;
      Tx0t[(size_t)(r0 + 2) * 64 + lane] = a2;
      Tx0t[(size_t)(r0 + 3) * 64 + lane] = a3;
    } else {
      int r0 = (q - 3000) * 4;
      const float* x0 = feato + (size_t)(r0 + 0) * 128;
      const float* x1 = feato + (size_t)(r0 + 1) * 128;
      const float* x2 = feato + (size_t)(r0 + 2) * 128;
      const float* x3 = feato + (size_t)(r0 + 3) * 128;
      float bv = bo[lane];
      float a0 = bv, a1 = bv, a2 = bv, a3 = bv;
      for (int k = 0; k < 128; ++k) {
        float wv = Wo[k * 64 + lane];
        a0 = fmaf(x0[k], wv, a0);
        a1 = fmaf(x1[k], wv, a1);
        a2 = fmaf(x2[k], wv, a2);
        a3 = fmaf(x3[k], wv, a3);
      }
      Tx0o[(size_t)(r0 + 0) * 64 + lane] = a0;
      Tx0o[(size_t)(r0 + 1) * 64 + lane] = a1;
      Tx0o[(size_t)(r0 + 2) * 64 + lane] = a2;
      Tx0o[(size_t)(r0 + 3) * 64 + lane] = a3;
    }
  }
}

// rs = 1/sqrt(max(cnt,1)); chunk-local exclusive scans (48 blocks)
__global__ __launch_bounds__(1024) void k_rsScan(
    const int* __restrict__ cnt, float* __restrict__ rs,
    int* __restrict__ rp0, int* __restrict__ rp1, int* __restrict__ rp2,
    int* __restrict__ ctot) {
  __shared__ int wsums[16];
  int tid = threadIdx.x, lane = tid & 63, wid = tid >> 6;
  for (int i = blockIdx.x * 1024 + tid; i < 96000; i += 48 * 1024)
    rs[i] = 1.0f / sqrtf(fmaxf((float)cnt[i], 1.0f));
  int ct = blockIdx.x;
  int rel, chunk;
  if (ct < 12) { rel = 0; chunk = ct; }
  else if (ct < 36) { rel = 1; chunk = ct - 12; }
  else { rel = 2; chunk = ct - 36; }
  int n = (rel == 1) ? NO : NT;
  const int* cdp = cnt + ((rel == 0) ? OCD0 : (rel == 1) ? OCD1 : OCD2);
  int* rpp = (rel == 0) ? rp0 : (rel == 1) ? rp1 : rp2;
  int i = chunk * 1024 + tid;
  int vI = (i < n) ? cdp[i] : 0;
  int s = vI;
#pragma unroll
  for (int d = 1; d < 64; d <<= 1) { int t = __shfl_up(s, d, 64); if (lane >= d) s += t; }
  if (lane == 63) wsums[wid] = s;
  __syncthreads();
  if (tid < 16) {
    int w = wsums[tid];
#pragma unroll
    for (int d = 1; d < 16; d <<= 1) { int t = __shfl_up(w, d, 64); if (tid >= d) w += t; }
    wsums[tid] = w;
  }
  __syncthreads();
  int wbase = wid ? wsums[wid - 1] : 0;
  if (i < n) rpp[i] = wbase + s - vI;
  if (tid == 0) ctot[rel * 40 + chunk] = wsums[15];
}

// chunk-base fix (block-local 48-entry prefix)
__global__ __launch_bounds__(256) void k_rpfix(
    int* __restrict__ rp0, int* __restrict__ rp1, int* __restrict__ rp2,
    const int* __restrict__ ctot) {
  __shared__ int cb[120];
  if (threadIdx.x == 0) {
    int b = 0;
    for (int c = 0; c < 12; ++c) { cb[c] = b; b += ctot[c]; }
    if (blockIdx.x == 0) rp0[NT] = b;
    b = 0;
    for (int c = 0; c < 24; ++c) { cb[40 + c] = b; b += ctot[40 + c]; }
    if (blockIdx.x == 0) rp1[NO] = b;
    b = 0;
    for (int c = 0; c < 12; ++c) { cb[80 + c] = b; b += ctot[80 + c]; }
    if (blockIdx.x == 0) rp2[NT] = b;
  }
  __syncthreads();
  int i = blockIdx.x * 256 + threadIdx.x;
  int TOT = gridDim.x * 256;
  for (int j = i; j < NT; j += TOT) rp0[j] += cb[j >> 10];
  for (int j = i; j < NO; j += TOT) rp1[j] += cb[40 + (j >> 10)];
  for (int j = i; j < NT; j += TOT) rp2[j] += cb[80 + (j >> 10)];
}

__global__ void k_fill(
    const int* __restrict__ sr0, const int* __restrict__ ds0,
    const int* __restrict__ sr1, const int* __restrict__ ds1,
    const int* __restrict__ sr2, const int* __restrict__ ds2,
    const int* __restrict__ rp0, const int* __restrict__ rp1,
    const int* __restrict__ rp2, int* __restrict__ fil,
    const float* __restrict__ rs,
    EP* __restrict__ ep0, EP* __restrict__ ep1, EP* __restrict__ ep2) {
  int gtid = blockIdx.x * 256 + threadIdx.x;
  int TOT = gridDim.x * 256;
  for (int e = gtid; e < E0C; e += TOT) {
    int d = ds0[e];
    int pos = rp0[d] + atomicAdd(&fil[d], 1);
    EP pk; pk.s = sr0[e]; pk.w = rs[OCS0 + pk.s];
    ep0[pos] = pk;
  }
  for (int e = gtid; e < E1C; e += TOT) {
    int d = ds1[e];
    int pos = rp1[d] + atomicAdd(&fil[12000 + d], 1);
    EP pk; pk.s = sr1[e]; pk.w = rs[OCS1 + pk.s];
    ep1[pos] = pk;
  }
  for (int e = gtid; e < E2C; e += TOT) {
    int d = ds2[e];
    int pos = rp2[d] + atomicAdd(&fil[36000 + d], 1);
    EP pk; pk.s = sr2[e]; pk.w = rs[OCS2 + pk.s];
    ep2[pos] = pk;
  }
}

// layer-1: all 3 relation GraphConvs; r2 branch also saves raw agg = A_0
__global__ __launch_bounds__(256) void k_layer1(
    const float* __restrict__ Tx0t, const float* __restrict__ Tx0o,
    const float* __restrict__ rs,
    const int* __restrict__ rp0, const EP* __restrict__ ep0,
    const int* __restrict__ rp1, const EP* __restrict__ ep1,
    const int* __restrict__ rp2, const EP* __restrict__ ep2,
    const float* __restrict__ W1r0, const float* __restrict__ b1r0,
    const float* __restrict__ W1r1, const float* __restrict__ b1r1,
    const float* __restrict__ W1r2, const float* __restrict__ b1r2,
    const float* __restrict__ a1W, const float* __restrict__ a1b,
    const float* __restrict__ a1v,
    float* __restrict__ mt0L, float* __restrict__ m2A, float* __restrict__ Tx1o,
    float* __restrict__ aggB0, float* __restrict__ sc) {
  __shared__ float sm[4][64];
  int wid = threadIdx.x >> 6, lane = threadIdx.x & 63;
  int t = blockIdx.x * 4 + wid;
  if (t < NT) {
    rowaggD(Tx0o, ep0, rp0, rs[OCD0 + t], W1r0, b1r0, mt0L, t, lane, sm[wid],
            a1W, a1b, a1v, sc + 0 * SCSTRIDE, nullptr);
  } else if (t < 2 * NT) {
    int r = t - NT;
    rowaggD(Tx0t, ep2, rp2, rs[OCD2 + r], W1r2, b1r2, m2A, r, lane, sm[wid],
            a1W, a1b, a1v, sc + 1 * SCSTRIDE, aggB0);  // raw = G(S_0) = A_0
  } else {
    int r = t - 2 * NT;
    rowaggD(Tx0t, ep1, rp1, rs[OCD1 + r], W1r1, b1r1, Tx1o, r, lane, sm[wid],
            nullptr, nullptr, nullptr, nullptr, nullptr);
  }
}

// layer-1 combine + GPR heads 0,1 fused with invariant mt0b rowagg
__global__ __launch_bounds__(256) void k_comb1(
    const float* __restrict__ Tx0t, const float* __restrict__ mt0L,
    const float* __restrict__ m2A, const float* __restrict__ Tx1o,
    const float* __restrict__ rs,
    const int* __restrict__ rp0, const EP* __restrict__ ep0,
    const float* __restrict__ W2r0, const float* __restrict__ b2r0,
    const float* __restrict__ a2W, const float* __restrict__ a2b,
    const float* __restrict__ a2v,
    const float* __restrict__ projW, const float* __restrict__ projb,
    const float* __restrict__ gamma,
    float* __restrict__ Tx1t, float* __restrict__ hidden, float* __restrict__ mt0b,
    float* __restrict__ sc) {
  __shared__ float smA[4][64];
  __shared__ float smB[4][64];
  int wid = threadIdx.x >> 6, lane = threadIdx.x & 63;
  int t = blockIdx.x * 4 + wid;
  if (t < NT) {
    int r = t;
    size_t o = (size_t)r * 64 + lane;
    float t0 = Tx0t[o];
    float m0v = mt0L[o];
    float m2v = m2A[o];
    float s0 = scSum(sc, 0, lane) * INV_NT;
    float s1 = scSum(sc, 1, lane) * INV_NT;
    float mx = fmaxf(s0, s1);
    float e0 = expf(s0 - mx), e1 = expf(s1 - mx);
    float inv = 1.0f / (e0 + e1);
    float t1v = e0 * inv * m0v + e1 * inv * m2v;
    Tx1t[o] = t1v;
    smA[wid][lane] = t0;
    smB[wid][lane] = t1v;
    int half = lane >> 5, hl = lane & 31;
    const float* pw = projW + (size_t)half * 2048;
    const float* src = half ? smB[wid] : smA[wid];
    float pa = projb[half * 32 + hl];
#pragma unroll 8
    for (int k = 0; k < 64; ++k)
      pa = fmaf(src[k], pw[k * 32 + hl], pa);
    float part = tanhf(pa) * gamma[hl * (KORD + 1) + half];
#pragma unroll
    for (int d = 16; d >= 1; d >>= 1) part += __shfl_xor(part, d, 64);
    float eta0 = __shfl(part, 0, 64) * (1.0f / 32.0f);
    float eta1 = __shfl(part, 32, 64) * (1.0f / 32.0f);
    hidden[o] = t0 * eta0 + t1v * eta1;
  } else {
    int r = t - NT;
    rowaggD(Tx1o, ep0, rp0, rs[OCD0 + r], W2r0, b2r0, mt0b, r, lane, smA[wid],
            a2W, a2b, a2v, sc + 2 * SCSTRIDE, nullptr);
  }
}

// j=1: blocks<3000 gather S_1 -> A_1 raw + mt2_1 + score slot 3;
// blocks>=3000: invariant g0 = G(mt0b).
__global__ __launch_bounds__(256) void k_iter1(
    const float* __restrict__ Tx1t, const float* __restrict__ mt0b,
    const float* __restrict__ rsd2, const int* __restrict__ rp2,
    const EP* __restrict__ ep2,
    const float* __restrict__ W, const float* __restrict__ bW,
    const float* __restrict__ fcW, const float* __restrict__ fcb,
    const float* __restrict__ av,
    float* __restrict__ mtdst, float* __restrict__ aggB1,
    float* __restrict__ g0, float* __restrict__ scoreNew) {
  __shared__ float sm[4][64];
  int wid = threadIdx.x >> 6, lane = threadIdx.x & 63;
  if (blockIdx.x < 3000) {
    int row = blockIdx.x * 4 + wid;
    rowaggD(Tx1t, ep2, rp2, rsd2[row], W, bW, mtdst, row, lane, sm[wid],
            fcW, fcb, av, scoreNew, aggB1);
  } else {
    int r = blockIdx.x * 4 + wid - NT;
    g0[(size_t)r * 64 + lane] = gatherEP(ep2, rp2[r], rp2[r + 1], mt0b, lane);
  }
}

// Fused GPR iteration j>=2 (ONE dispatch); LDS-broadcast GEMMs.
// Gather issued first so its VMEM latency overlaps the scSum L2 reads.
__global__ __launch_bounds__(256) void k_iterF(
    const float* __restrict__ mt2prev, const float* __restrict__ g0,
    float* __restrict__ agg,  // read A_{j-2}, write A_j (same element, same thread)
    const float* __restrict__ mt0b, const float* __restrict__ Tsrc2,
    float* __restrict__ Tdst,
    const float* __restrict__ rsd2, const int* __restrict__ rp2,
    const EP* __restrict__ ep2,
    const float* __restrict__ W, const float* __restrict__ bW,
    const float* __restrict__ fcW, const float* __restrict__ fcb,
    const float* __restrict__ av,
    const float* __restrict__ sc, int slotPrev, float* __restrict__ scoreNew,
    const float* __restrict__ projW, const float* __restrict__ projb,
    const float* __restrict__ gamma, int kidx,
    float* __restrict__ hidden, float* __restrict__ mtdst) {
  __shared__ float sm[4][64];
  int wid = threadIdx.x >> 6, lane = threadIdx.x & 63;
  float* smrow = sm[wid];
  int r = blockIdx.x * 4 + wid;
  float gm = gatherEP(ep2, rp2[r], rp2[r + 1], mt2prev, lane);
  float s0 = scSum(sc, 2, lane) * INV_NT;
  float s1 = scSum(sc, slotPrev, lane) * INV_NT;
  float mx = fmaxf(s0, s1);
  float e0 = expf(s0 - mx), e1 = expf(s1 - mx);
  float inv = 1.0f / (e0 + e1);
  float tw0 = 2.0f * e0 * inv, tw1 = 2.0f * e1 * inv;
  size_t o = (size_t)r * 64 + lane;
  float aggj = fmaf(tw0, g0[o], fmaf(tw1, gm, -agg[o]));
  agg[o] = aggj;
  smrow[lane] = aggj * rsd2[r];
  float m = bW[lane];
#pragma unroll 8
  for (int k = 0; k < 64; ++k) m = fmaf(smrow[k], W[k * 64 + lane], m);
  mtdst[o] = m;
  smrow[lane] = m;
  float fa = fcb[lane];
#pragma unroll 8
  for (int k = 0; k < 64; ++k) fa = fmaf(smrow[k], fcW[k * 64 + lane], fa);
  float part = waveSum(tanhf(fa) * av[lane]);
  if (lane == 0) atomicAdd(&scoreNew[(blockIdx.x & 63) * 16], part);
  float tj = fmaf(tw0, mt0b[o], fmaf(tw1, mt2prev[o], -Tsrc2[o]));
  Tdst[o] = tj;
  smrow[lane] = tj;
  float eta = gprEta(smrow, projW, projb, gamma, kidx, lane);
  hidden[o] += tj * eta;
}

// T10 fold + h=tanh -> out, logits, loss partial, stage-1 MLP for h and z_p
__global__ __launch_bounds__(256) void k_post1(
    float* __restrict__ hidden, const float* __restrict__ mt0b,
    const float* __restrict__ mt9, const float* __restrict__ T8,
    const float* __restrict__ sc,
    const float* __restrict__ projW, const float* __restrict__ projb,
    const float* __restrict__ gamma,
    const float* __restrict__ z_pre,
    const float* __restrict__ p3W, const float* __restrict__ p3b,
    const float* __restrict__ outW, const float* __restrict__ outb,
    const float* __restrict__ p1W1, const float* __restrict__ p1b1,
    float* __restrict__ outH, float* __restrict__ outLogits,
    float* __restrict__ t1, float* __restrict__ t1z,
    float* __restrict__ lossAcc) {
  __shared__ float smH[4][64];
  __shared__ float smZ[4][64];
  int wid = threadIdx.x >> 6, lane = threadIdx.x & 63;
  int row = blockIdx.x * 4 + wid;
  size_t o = (size_t)row * 64 + lane;
  float s0 = scSum(sc, 2, lane) * INV_NT;
  float s1 = scSum(sc, 11, lane) * INV_NT;
  float mx = fmaxf(s0, s1);
  float e0 = expf(s0 - mx), e1 = expf(s1 - mx);
  float inv = 1.0f / (e0 + e1);
  float tw0 = 2.0f * e0 * inv, tw1 = 2.0f * e1 * inv;
  float t10 = fmaf(tw0, mt0b[o], fmaf(tw1, mt9[o], -T8[o]));
  smH[wid][lane] = t10;
  float eta = gprEta(smH[wid], projW, projb, gamma, KORD, lane);
  float hfin = hidden[o] + t10 * eta;
  hidden[o] = hfin;  // adj reads this
  float hv = tanhf(hfin);
  outH[o] = hv;
  const float* zr = z_pre + (size_t)row * 128;
  float zpv = p3b[lane];
  for (int k = 0; k < 128; ++k) zpv = fmaf(zr[k], p3W[k * 64 + lane], zpv);
  smH[wid][lane] = hv;
  smZ[wid][lane] = zpv;
  float hm = waveSum(hv) * (1.0f / 64.0f);
  float zm = waveSum(zpv) * (1.0f / 64.0f);
  float cv = waveSum((hv - hm) * (zpv - zm)) * (1.0f / 64.0f);
  if (lane == 0) atomicAdd(&lossAcc[(blockIdx.x & 63) * 16], cv);
#pragma unroll
  for (int j = 0; j < 3; ++j) {
    float pj = waveSum(hv * outW[lane * 3 + j]);
    if (lane == 0) outLogits[row * 3 + j] = pj + outb[j];
  }
  float a0 = p1b1[lane], a1 = p1b1[64 + lane];
  float z0 = a0, z1 = a1;
#pragma unroll 4
  for (int k = 0; k < 64; ++k) {
    float hk = smH[wid][k];
    float zk = smZ[wid][k];
    float wlo = p1W1[k * 128 + lane], whi = p1W1[k * 128 + 64 + lane];
    a0 = fmaf(hk, wlo, a0); a1 = fmaf(hk, whi, a1);
    z0 = fmaf(zk, wlo, z0); z1 = fmaf(zk, whi, z1);
  }
  t1[(size_t)row * 128 + lane] = fmaxf(a0, 0.f);
  t1[(size_t)row * 128 + 64 + lane] = fmaxf(a1, 0.f);
  t1z[(size_t)row * 128 + lane] = fmaxf(z0, 0.f);
  t1z[(size_t)row * 128 + 64 + lane] = fmaxf(z1, 0.f);
}

// Fused: blocks [0,NADJ) = C=H@H^T triangular tiles; blocks >= NADJ = stage-2
// MLP (LDS-broadcast GEMM) + loss finalize.
__global__ __launch_bounds__(256) void k_adjpost(
    const float* __restrict__ H, float* __restrict__ C, int N,
    const float* __restrict__ t1, const float* __restrict__ t1z,
    const float* __restrict__ p1W2, const float* __restrict__ p1b2,
    float* __restrict__ xpre, float* __restrict__ zpre1,
    const float* __restrict__ lossAcc, float* __restrict__ outLoss) {
  __shared__ float sh[4224];  // As = sh[0..2111] (16x132), Bs = sh[2112..4223]
  int b = blockIdx.x;
  if (b < NADJ) {
    int bi = 0, idx = b, rowlen = NB;
    while (idx >= rowlen) { idx -= rowlen; --rowlen; ++bi; }
    int bj = bi + idx;
    int tid = threadIdx.x;
    int tx = tid & 15, ty = tid >> 4;
    int rb = tid & 127, halfq = tid >> 7;  // load indexing
    float acc[8][8] = {};
    for (int kt = 0; kt < 64; kt += 16) {
      {
        int gi = bi * 128 + rb;
        int gj = bj * 128 + rb;
#pragma unroll
        for (int l = 0; l < 2; ++l) {
          int kk = (halfq * 2 + l) * 4;
          float4 a = (gi < N) ? *reinterpret_cast<const float4*>(&H[(size_t)gi * 64 + kt + kk])
                              : make_float4(0.f, 0.f, 0.f, 0.f);
          sh[(kk + 0) * 132 + rb] = a.x; sh[(kk + 1) * 132 + rb] = a.y;
          sh[(kk + 2) * 132 + rb] = a.z; sh[(kk + 3) * 132 + rb] = a.w;
          float4 bb = (gj < N) ? *reinterpret_cast<const float4*>(&H[(size_t)gj * 64 + kt + kk])
                               : make_float4(0.f, 0.f, 0.f, 0.f);
          sh[2112 + (kk + 0) * 132 + rb] = bb.x; sh[2112 + (kk + 1) * 132 + rb] = bb.y;
          sh[2112 + (kk + 2) * 132 + rb] = bb.z; sh[2112 + (kk + 3) * 132 + rb] = bb.w;
        }
      }
      __syncthreads();
#pragma unroll 8
      for (int k = 0; k < 16; ++k) {
        float4 a0 = *reinterpret_cast<const float4*>(&sh[k * 132 + ty * 4]);
        float4 a1 = *reinterpret_cast<const float4*>(&sh[k * 132 + 64 + ty * 4]);
        float4 b0 = *reinterpret_cast<const float4*>(&sh[2112 + k * 132 + tx * 4]);
        float4 b1 = *reinterpret_cast<const float4*>(&sh[2112 + k * 132 + 64 + tx * 4]);
        float av[8] = {a0.x, a0.y, a0.z, a0.w, a1.x, a1.y, a1.z, a1.w};
        float bv[8] = {b0.x, b0.y, b0.z, b0.w, b1.x, b1.y, b1.z, b1.w};
#pragma unroll
        for (int i = 0; i < 8; ++i)
#pragma unroll
          for (int j = 0; j < 8; ++j) acc[i][j] = fmaf(av[i], bv[j], acc[i][j]);
      }
      __syncthreads();
    }
#pragma unroll
    for (int g = 0; g < 2; ++g) {
#pragma unroll
      for (int i = 0; i < 4; ++i) {
        int gr = bi * 128 + g * 64 + ty * 4 + i;
        if (gr >= N) continue;
#pragma unroll
        for (int h = 0; h < 2; ++h) {
          int gc = bj * 128 + h * 64 + tx * 4;
          if (gc >= N) continue;
          nfloat4 vv = {acc[g * 4 + i][h * 4 + 0], acc[g * 4 + i][h * 4 + 1],
                        acc[g * 4 + i][h * 4 + 2], acc[g * 4 + i][h * 4 + 3]};
          *reinterpret_cast<nfloat4*>(&C[(size_t)gr * N + gc]) = vv;
        }
      }
    }
    if (bi != bj) {
      float* T = sh;
      int cc = tid >> 4, f4 = tid & 15;
#pragma unroll
      for (int g = 0; g < 2; ++g) {
#pragma unroll
        for (int h = 0; h < 2; ++h) {
          __syncthreads();
#pragma unroll
          for (int i = 0; i < 4; ++i) {
            int r = ty * 4 + i;
#pragma unroll
            for (int j = 0; j < 4; ++j)
              T[r * 65 + tx * 4 + j] = acc[g * 4 + i][h * 4 + j];
          }
          __syncthreads();
          int gr0 = bi * 128 + g * 64 + f4 * 4;
#pragma unroll
          for (int c0 = 0; c0 < 64; c0 += 16) {
            int c = c0 + cc;
            int gc = bj * 128 + h * 64 + c;
            if (gc < N) {
              nfloat4 v = {T[(f4 * 4 + 0) * 65 + c], T[(f4 * 4 + 1) * 65 + c],
                           T[(f4 * 4 + 2) * 65 + c], T[(f4 * 4 + 3) * 65 + c]};
              *reinterpret_cast<nfloat4*>(&C[(size_t)gc * N + gr0]) = v;
            }
          }
        }
      }
    }
    return;
  }
  // ---- post2 part: stage-1 rows in wave-local LDS, broadcast GEMM ----
  int qb = b - NADJ;  // 0..1499
  if (qb == 0 && threadIdx.x < 64) {
    float v = waveSum(lossAcc[threadIdx.x * 16]);
    if (threadIdx.x == 0) {
      float s = v * (1.0f / NT);
      outLoss[0] = s * s;  // loss_dis1 (1-row HSIC) is exactly 0
    }
  }
  int wid = threadIdx.x >> 6, lane = threadIdx.x & 63;
  int q = qb * 4 + wid;  // 0..5999
  bool isz = q >= 3000;
  int r0 = (isz ? q - 3000 : q) * 4;
  const float* T = isz ? t1z : t1;
  float* D = isz ? zpre1 : xpre;
  float* shp = sh + wid * 520;  // 4 rows x 130 stride (wave-private)
#pragma unroll
  for (int rr = 0; rr < 4; ++rr) {
    shp[rr * 130 + lane] = T[(size_t)(r0 + rr) * 128 + lane];
    shp[rr * 130 + 64 + lane] = T[(size_t)(r0 + rr) * 128 + 64 + lane];
  }
  for (int c0 = 0; c0 < 384; c0 += 64) {
    int c = c0 + lane;
    bool ok = c < 334;
    float bb = ok ? p1b2[c] : 0.f;
    float acc0 = bb, acc1 = bb, acc2 = bb, acc3 = bb;
#pragma unroll 4
    for (int k = 0; k < 128; ++k) {
      float w = ok ? p1W2[k * 334 + c] : 0.f;
      acc0 = fmaf(shp[0 * 130 + k], w, acc0);
      acc1 = fmaf(shp[1 * 130 + k], w, acc1);
      acc2 = fmaf(shp[2 * 130 + k], w, acc2);
      acc3 = fmaf(shp[3 * 130 + k], w, acc3);
    }
    if (ok) {
      D[(size_t)(r0 + 0) * 334 + c] = tanhf(acc0);
      D[(size_t)(r0 + 1) * 334 + c] = tanhf(acc1);
      D[(size_t)(r0 + 2) * 334 + c] = tanhf(acc2);
      D[(size_t)(r0 + 3) * 334 + c] = tanhf(acc3);
    }
  }
}

extern "C" void kernel_launch(void* const* d_in, const int* in_sizes, int n_in,
                              void* d_out, int out_size, void* d_ws, size_t ws_size,
                              hipStream_t stream) {
  const float* features_v1 = (const float*)d_in[0];
  const float* feat_other = (const float*)d_in[1];
  const float* z_pre = (const float*)d_in[2];
  const float* Wt = (const float*)d_in[3];  const float* bt = (const float*)d_in[4];
  const float* Wo = (const float*)d_in[5];  const float* bo = (const float*)d_in[6];
  const float* W1r0 = (const float*)d_in[7];  const float* b1r0 = (const float*)d_in[8];
  const float* W1r1 = (const float*)d_in[9];  const float* b1r1 = (const float*)d_in[10];
  const float* W1r2 = (const float*)d_in[11]; const float* b1r2 = (const float*)d_in[12];
  const float* a1W = (const float*)d_in[13]; const float* a1b = (const float*)d_in[14];
  const float* a1v = (const float*)d_in[15];
  const float* W2r0 = (const float*)d_in[16]; const float* b2r0 = (const float*)d_in[17];
  // d_in[18]/d_in[19] (W2r1/b2r1) feed only the discarded loop out_o — unused.
  const float* W2r2 = (const float*)d_in[20]; const float* b2r2 = (const float*)d_in[21];
  const float* a2W = (const float*)d_in[22]; const float* a2b = (const float*)d_in[23];
  const float* a2v = (const float*)d_in[24];
  const float* projW = (const float*)d_in[25]; const float* projb = (const float*)d_in[26];
  const float* gamma = (const float*)d_in[27];
  const float* p3W = (const float*)d_in[28]; const float* p3b = (const float*)d_in[29];
  const float* p1W1 = (const float*)d_in[30]; const float* p1b1 = (const float*)d_in[31];
  const float* p1W2 = (const float*)d_in[32]; const float* p1b2 = (const float*)d_in[33];
  const float* outW = (const float*)d_in[34]; const float* outb = (const float*)d_in[35];
  const int* sr0 = (const int*)d_in[36]; const int* ds0 = (const int*)d_in[37];
  const int* sr1 = (const int*)d_in[38]; const int* ds1 = (const int*)d_in[39];
  const int* sr2 = (const int*)d_in[40]; const int* ds2 = (const int*)d_in[41];

  float* out = (float*)d_out;
  const size_t LOGITS_OFF = 0;
  const size_t H_OFF = (size_t)NT * 3;
  const size_t XPRE_OFF = H_OFF + (size_t)NT * 64;
  const size_t ZPRE_OFF = XPRE_OFF + (size_t)NT * 334;
  const size_t ADJ_OFF = ZPRE_OFF + (size_t)NT * 334;
  const size_t LOSS_OFF = ADJ_OFF + (size_t)NT * NT;

  float* ws = (float*)d_ws;
  size_t o = 0;
  auto alloc = [&](size_t n) { float* p = ws + o; o += n; return p; };
  float* Tbuf0 = alloc((size_t)NT * 64);   // S_0 (= Tx0t)
  float* Tbuf1 = alloc((size_t)NT * 64);   // S_1
  float* Tbuf2 = alloc((size_t)NT * 64);
  float* Tx0o = alloc((size_t)NO * 64);
  float* Tx1o = alloc((size_t)NO * 64);
  float* mt0L = alloc((size_t)NT * 64);
  float* mt0b = alloc((size_t)NT * 64);
  float* m2A  = alloc((size_t)NT * 64);
  float* m2B  = alloc((size_t)NT * 64);
  float* hidden = alloc((size_t)NT * 64);
  float* t1   = alloc((size_t)NT * 128);
  float* t1z  = alloc((size_t)NT * 128);
  float* g0   = alloc((size_t)NT * 64);   // G(mt0b), loop-invariant
  float* aggB0 = alloc((size_t)NT * 64);  // A_{even}
  float* aggB1 = alloc((size_t)NT * 64);  // A_{odd}
  float* rs   = alloc(96000);
  // score slots 0..11 (1024 floats each, 64 buckets x 16 stride), loss = slot 12
  float* sc   = alloc(13 * SCSTRIDE);  // memset region starts here
  int* cnt = (int*)(ws + o); o += 96000;
  int* fil = (int*)(ws + o); o += 48000;
  int* rp0 = (int*)(ws + o); o += NT + 1;
  int* rp1 = (int*)(ws + o); o += NO + 1;
  int* rp2 = (int*)(ws + o); o += NT + 1;
  int* ctot = (int*)(ws + o); o += 120;
  o = (o + 1) & ~(size_t)1;  // 8-byte align for EP arrays
  EP* ep0 = (EP*)(ws + o); o += (size_t)E0C * 2;
  EP* ep1 = (EP*)(ws + o); o += (size_t)E1C * 2;
  EP* ep2 = (EP*)(ws + o); o += (size_t)E2C * 2;

  // zero accumulators: sc(13*1024) + cnt(96000) + fil(48000), contiguous
  (void)hipMemsetAsync(sc, 0, (13 * SCSTRIDE + 96000 + 48000) * sizeof(float), stream);

  k_histproj<<<2048, 256, 0, stream>>>(sr0, ds0, sr1, ds1, sr2, ds2, cnt,
                                       features_v1, feat_other, Wt, bt, Wo, bo,
                                       Tbuf0, Tx0o);
  k_rsScan<<<48, 1024, 0, stream>>>(cnt, rs, rp0, rp1, rp2, ctot);
  k_rpfix<<<256, 256, 0, stream>>>(rp0, rp1, rp2, ctot);
  k_fill<<<2048, 256, 0, stream>>>(sr0, ds0, sr1, ds1, sr2, ds2, rp0, rp1, rp2,
                                   fil, rs, ep0, ep1, ep2);
  k_layer1<<<12000, 256, 0, stream>>>(Tbuf0, Tx0o, rs,
                                      rp0, ep0, rp1, ep1, rp2, ep2,
                                      W1r0, b1r0, W1r1, b1r1, W1r2, b1r2,
                                      a1W, a1b, a1v, mt0L, m2A, Tx1o, aggB0, sc);
  k_comb1<<<6000, 256, 0, stream>>>(Tbuf0, mt0L, m2A, Tx1o, rs, rp0, ep0,
                                    W2r0, b2r0, a2W, a2b, a2v,
                                    projW, projb, gamma,
                                    Tbuf1, hidden, mt0b, sc);

  float* Tb[3] = {Tbuf0, Tbuf1, Tbuf2};
  float* Mb[2] = {m2A, m2B};
  float* Ab[2] = {aggB0, aggB1};
  const float* rsd2 = rs + OCD2;
  // j=1: gather S_1 -> A_1 + mt2_1 (Mb[1]) + score slot 3; also g0 = G(mt0b)
  k_iter1<<<6000, 256, 0, stream>>>(Tbuf1, mt0b, rsd2, rp2, ep2,
                                    W2r2, b2r2, a2W, a2b, a2v,
                                    Mb[1], aggB1, g0, sc + 3 * SCSTRIDE);
  for (int j = 2; j <= 9; ++j) {
    k_iterF<<<3000, 256, 0, stream>>>(Mb[(j - 1) & 1], g0, Ab[j & 1],
                                      mt0b, Tb[(j - 2) % 3], Tb[j % 3],
                                      rsd2, rp2, ep2, W2r2, b2r2,
                                      a2W, a2b, a2v, sc, 2 + j - 1,
                                      sc + (2 + j) * SCSTRIDE,
                                      projW, projb, gamma, j,
                                      hidden, Mb[j & 1]);
  }
  // S_9 in Tb[0]; S_8 in Tb[2]; mt2_9 in Mb[1]

  k_post1<<<3000, 256, 0, stream>>>(hidden, mt0b, Mb[1], Tb[2], sc,
                                    projW, projb, gamma, z_pre, p3W, p3b,
                                    outW, outb, p1W1, p1b1,
                                    out + H_OFF, out + LOGITS_OFF, t1, t1z,
                                    sc + 12 * SCSTRIDE);
  k_adjpost<<<NADJ + 1500, 256, 0, stream>>>(hidden, out + ADJ_OFF, NT,
                                             t1, t1z, p1W2, p1b2,
                                             out + XPRE_OFF, out + ZPRE_OFF,
                                             sc + 12 * SCSTRIDE, out + LOSS_OFF);
}

// Round 14
// 971.396 us; speedup vs baseline: 1.8053x; 1.0090x over previous
//
#include <hip/hip_runtime.h>
#include <math.h>

#define NT 12000
#define NO 24000
#define KORD 10
#define E0C 384000
#define E1C 384000
#define E2C 192000
#define INV_NT (1.0f / 12000.0f)
#define NB 94              // ceil(12000/128) adj tiles
#define NADJ ((NB * (NB + 1)) / 2)  // 4465 triangular blocks
#define SCSTRIDE 1024      // one score slot = 64 buckets x 16-float stride

typedef float nfloat4 __attribute__((ext_vector_type(4)));

struct __align__(8) EP { int s; float w; };  // packed edge: src index + weight

// rs/cnt layout offsets: [cd0 NT][cd1 NO][cd2 NT][cs0 NO][cs1 NT][cs2 NT]
#define OCD0 0
#define OCD1 12000
#define OCD2 36000
#define OCS0 48000
#define OCS1 72000
#define OCS2 84000

static __device__ __forceinline__ float waveSum(float v) {
  v += __shfl_xor(v, 32, 64);
  v += __shfl_xor(v, 16, 64);
  v += __shfl_xor(v, 8, 64);
  v += __shfl_xor(v, 4, 64);
  v += __shfl_xor(v, 2, 64);
  v += __shfl_xor(v, 1, 64);
  return v;
}

// sum of a 64-bucket score slot (bucket i at stride 16 => 1 cache line each)
static __device__ __forceinline__ float scSum(const float* __restrict__ scb,
                                              int slot, int lane) {
  return waveSum(scb[slot * SCSTRIDE + lane * 16]);
}

// eta for proj head kidx; row vector in wave-local LDS row smrow[0..63]
static __device__ __forceinline__ float gprEta(const float* __restrict__ smrow,
                                               const float* __restrict__ pwAll,
                                               const float* __restrict__ pb,
                                               const float* __restrict__ gamma,
                                               int kidx, int lane) {
  int hl = lane & 31;
  const float* pw = pwAll + (size_t)kidx * 2048;
  float pa = pb[kidx * 32 + hl];
#pragma unroll 8
  for (int k = 0; k < 64; ++k)
    pa = fmaf(smrow[k], pw[k * 32 + hl], pa);
  float part = tanhf(pa) * gamma[hl * (KORD + 1) + kidx];
#pragma unroll
  for (int d = 16; d >= 1; d >>= 1) part += __shfl_xor(part, d, 64);
  return __shfl(part, 0, 64) * (1.0f / 32.0f);
}

// dual-acc 8-unroll CSR gather over packed edges
static __device__ __forceinline__ float gatherEP(
    const EP* __restrict__ ep, int p0, int p1,
    const float* __restrict__ X, int lane) {
  float a0 = 0.f, a1 = 0.f;
  int p = p0;
  for (; p + 7 < p1; p += 8) {
    EP e0 = ep[p], e1 = ep[p + 1], e2 = ep[p + 2], e3 = ep[p + 3];
    EP e4 = ep[p + 4], e5 = ep[p + 5], e6 = ep[p + 6], e7 = ep[p + 7];
    a0 = fmaf(X[(size_t)e0.s * 64 + lane], e0.w, a0);
    a1 = fmaf(X[(size_t)e1.s * 64 + lane], e1.w, a1);
    a0 = fmaf(X[(size_t)e2.s * 64 + lane], e2.w, a0);
    a1 = fmaf(X[(size_t)e3.s * 64 + lane], e3.w, a1);
    a0 = fmaf(X[(size_t)e4.s * 64 + lane], e4.w, a0);
    a1 = fmaf(X[(size_t)e5.s * 64 + lane], e5.w, a1);
    a0 = fmaf(X[(size_t)e6.s * 64 + lane], e6.w, a0);
    a1 = fmaf(X[(size_t)e7.s * 64 + lane], e7.w, a1);
  }
  for (; p < p1; ++p) { EP e = ep[p]; a0 = fmaf(X[(size_t)e.s * 64 + lane], e.w, a0); }
  return a0 + a1;
}

// CSR gather + deg-norm + (agg@W + b) + optional score/raw.
// GEMM via wave-local LDS broadcast row (smrow = this wave's private 64 floats).
static __device__ __forceinline__ void rowaggD(
    const float* __restrict__ X, const EP* __restrict__ ep,
    const int* __restrict__ rp, float rsdv,
    const float* __restrict__ W, const float* __restrict__ b,
    float* __restrict__ outp, int row, int lane, float* __restrict__ smrow,
    const float* fcW, const float* fcb, const float* av, float* score,
    float* __restrict__ rawAgg) {
  float acc = gatherEP(ep, rp[row], rp[row + 1], X, lane);
  if (rawAgg) rawAgg[(size_t)row * 64 + lane] = acc;
  smrow[lane] = acc * rsdv;
  float m = b[lane];
#pragma unroll 8
  for (int k = 0; k < 64; ++k) m = fmaf(smrow[k], W[k * 64 + lane], m);
  outp[(size_t)row * 64 + lane] = m;
  if (score) {
    smrow[lane] = m;
    float fa = fcb[lane];
#pragma unroll 8
    for (int k = 0; k < 64; ++k) fa = fmaf(smrow[k], fcW[k * 64 + lane], fa);
    float part = waveSum(tanhf(fa) * av[lane]);
    if (lane == 0) atomicAdd(&score[(blockIdx.x & 63) * 16], part);
  }
}

// degree histograms (6 arrays) + input projections (4-row tiling: 4x W reuse)
__global__ __launch_bounds__(256) void k_histproj(
    const int* __restrict__ sr0, const int* __restrict__ ds0,
    const int* __restrict__ sr1, const int* __restrict__ ds1,
    const int* __restrict__ sr2, const int* __restrict__ ds2,
    int* __restrict__ cnt,
    const float* __restrict__ features, const float* __restrict__ feato,
    const float* __restrict__ Wt, const float* __restrict__ bt,
    const float* __restrict__ Wo, const float* __restrict__ bo,
    float* __restrict__ Tx0t, float* __restrict__ Tx0o) {
  int gtid = blockIdx.x * 256 + threadIdx.x;
  int TOT = gridDim.x * 256;
  for (int i = gtid; i < E0C; i += TOT) {
    atomicAdd(&cnt[OCD0 + ds0[i]], 1);
    atomicAdd(&cnt[OCS0 + sr0[i]], 1);
  }
  for (int i = gtid; i < E1C; i += TOT) {
    atomicAdd(&cnt[OCD1 + ds1[i]], 1);
    atomicAdd(&cnt[OCS1 + sr1[i]], 1);
  }
  for (int i = gtid; i < E2C; i += TOT) {
    atomicAdd(&cnt[OCD2 + ds2[i]], 1);
    atomicAdd(&cnt[OCS2 + sr2[i]], 1);
  }
  int lane = threadIdx.x & 63;
  int gw = gtid >> 6, NW = TOT >> 6;
  for (int q = gw; q < 9000; q += NW) {
    if (q < 3000) {
      int r0 = q * 4;
      const float* x0 = features + (size_t)(r0 + 0) * 334;
      const float* x1 = features + (size_t)(r0 + 1) * 334;
      const float* x2 = features + (size_t)(r0 + 2) * 334;
      const float* x3 = features + (size_t)(r0 + 3) * 334;
      float bv = bt[lane];
      float a0 = bv, a1 = bv, a2 = bv, a3 = bv;
      for (int k = 0; k < 334; ++k) {
        float wv = Wt[k * 64 + lane];
        a0 = fmaf(x0[k], wv, a0);
        a1 = fmaf(x1[k], wv, a1);
        a2 = fmaf(x2[k], wv, a2);
        a3 = fmaf(x3[k], wv, a3);
      }
      Tx0t[(size_t)(r0 + 0) * 64 + lane] = a0;
      Tx0t[(size_t)(r0 + 1) * 64 + lane] = a1;
      Tx0t[(size_t)(r0 + 2) * 64 + lane] = a2;
      Tx0t[(size_t)(r0 + 3) * 64 + lane] = a3;
    } else {
      int r0 = (q - 3000) * 4;
      const float* x0 = feato + (size_t)(r0 + 0) * 128;
      const float* x1 = feato + (size_t)(r0 + 1) * 128;
      const float* x2 = feato + (size_t)(r0 + 2) * 128;
      const float* x3 = feato + (size_t)(r0 + 3) * 128;
      float bv = bo[lane];
      float a0 = bv, a1 = bv, a2 = bv, a3 = bv;
      for (int k = 0; k < 128; ++k) {
        float wv = Wo[k * 64 + lane];
        a0 = fmaf(x0[k], wv, a0);
        a1 = fmaf(x1[k], wv, a1);
        a2 = fmaf(x2[k], wv, a2);
        a3 = fmaf(x3[k], wv, a3);
      }
      Tx0o[(size_t)(r0 + 0) * 64 + lane] = a0;
      Tx0o[(size_t)(r0 + 1) * 64 + lane] = a1;
      Tx0o[(size_t)(r0 + 2) * 64 + lane] = a2;
      Tx0o[(size_t)(r0 + 3) * 64 + lane] = a3;
    }
  }
}

// rs = 1/sqrt(max(cnt,1)); chunk-local exclusive scans (48 blocks)
__global__ __launch_bounds__(1024) void k_rsScan(
    const int* __restrict__ cnt, float* __restrict__ rs,
    int* __restrict__ rp0, int* __restrict__ rp1, int* __restrict__ rp2,
    int* __restrict__ ctot) {
  __shared__ int wsums[16];
  int tid = threadIdx.x, lane = tid & 63, wid = tid >> 6;
  for (int i = blockIdx.x * 1024 + tid; i < 96000; i += 48 * 1024)
    rs[i] = 1.0f / sqrtf(fmaxf((float)cnt[i], 1.0f));
  int ct = blockIdx.x;
  int rel, chunk;
  if (ct < 12) { rel = 0; chunk = ct; }
  else if (ct < 36) { rel = 1; chunk = ct - 12; }
  else { rel = 2; chunk = ct - 36; }
  int n = (rel == 1) ? NO : NT;
  const int* cdp = cnt + ((rel == 0) ? OCD0 : (rel == 1) ? OCD1 : OCD2);
  int* rpp = (rel == 0) ? rp0 : (rel == 1) ? rp1 : rp2;
  int i = chunk * 1024 + tid;
  int vI = (i < n) ? cdp[i] : 0;
  int s = vI;
#pragma unroll
  for (int d = 1; d < 64; d <<= 1) { int t = __shfl_up(s, d, 64); if (lane >= d) s += t; }
  if (lane == 63) wsums[wid] = s;
  __syncthreads();
  if (tid < 16) {
    int w = wsums[tid];
#pragma unroll
    for (int d = 1; d < 16; d <<= 1) { int t = __shfl_up(w, d, 64); if (tid >= d) w += t; }
    wsums[tid] = w;
  }
  __syncthreads();
  int wbase = wid ? wsums[wid - 1] : 0;
  if (i < n) rpp[i] = wbase + s - vI;
  if (tid == 0) ctot[rel * 40 + chunk] = wsums[15];
}

// chunk-base fix (block-local 48-entry prefix)
__global__ __launch_bounds__(256) void k_rpfix(
    int* __restrict__ rp0, int* __restrict__ rp1, int* __restrict__ rp2,
    const int* __restrict__ ctot) {
  __shared__ int cb[120];
  if (threadIdx.x == 0) {
    int b = 0;
    for (int c = 0; c < 12; ++c) { cb[c] = b; b += ctot[c]; }
    if (blockIdx.x == 0) rp0[NT] = b;
    b = 0;
    for (int c = 0; c < 24; ++c) { cb[40 + c] = b; b += ctot[40 + c]; }
    if (blockIdx.x == 0) rp1[NO] = b;
    b = 0;
    for (int c = 0; c < 12; ++c) { cb[80 + c] = b; b += ctot[80 + c]; }
    if (blockIdx.x == 0) rp2[NT] = b;
  }
  __syncthreads();
  int i = blockIdx.x * 256 + threadIdx.x;
  int TOT = gridDim.x * 256;
  for (int j = i; j < NT; j += TOT) rp0[j] += cb[j >> 10];
  for (int j = i; j < NO; j += TOT) rp1[j] += cb[40 + (j >> 10)];
  for (int j = i; j < NT; j += TOT) rp2[j] += cb[80 + (j >> 10)];
}

__global__ void k_fill(
    const int* __restrict__ sr0, const int* __restrict__ ds0,
    const int* __restrict__ sr1, const int* __restrict__ ds1,
    const int* __restrict__ sr2, const int* __restrict__ ds2,
    const int* __restrict__ rp0, const int* __restrict__ rp1,
    const int* __restrict__ rp2, int* __restrict__ fil,
    const float* __restrict__ rs,
    EP* __restrict__ ep0, EP* __restrict__ ep1, EP* __restrict__ ep2) {
  int gtid = blockIdx.x * 256 + threadIdx.x;
  int TOT = gridDim.x * 256;
  for (int e = gtid; e < E0C; e += TOT) {
    int d = ds0[e];
    int pos = rp0[d] + atomicAdd(&fil[d], 1);
    EP pk; pk.s = sr0[e]; pk.w = rs[OCS0 + pk.s];
    ep0[pos] = pk;
  }
  for (int e = gtid; e < E1C; e += TOT) {
    int d = ds1[e];
    int pos = rp1[d] + atomicAdd(&fil[12000 + d], 1);
    EP pk; pk.s = sr1[e]; pk.w = rs[OCS1 + pk.s];
    ep1[pos] = pk;
  }
  for (int e = gtid; e < E2C; e += TOT) {
    int d = ds2[e];
    int pos = rp2[d] + atomicAdd(&fil[36000 + d], 1);
    EP pk; pk.s = sr2[e]; pk.w = rs[OCS2 + pk.s];
    ep2[pos] = pk;
  }
}

// layer-1: all 3 relation GraphConvs; r2 branch also saves raw agg = A_0
__global__ __launch_bounds__(256) void k_layer1(
    const float* __restrict__ Tx0t, const float* __restrict__ Tx0o,
    const float* __restrict__ rs,
    const int* __restrict__ rp0, const EP* __restrict__ ep0,
    const int* __restrict__ rp1, const EP* __restrict__ ep1,
    const int* __restrict__ rp2, const EP* __restrict__ ep2,
    const float* __restrict__ W1r0, const float* __restrict__ b1r0,
    const float* __restrict__ W1r1, const float* __restrict__ b1r1,
    const float* __restrict__ W1r2, const float* __restrict__ b1r2,
    const float* __restrict__ a1W, const float* __restrict__ a1b,
    const float* __restrict__ a1v,
    float* __restrict__ mt0L, float* __restrict__ m2A, float* __restrict__ Tx1o,
    float* __restrict__ aggB0, float* __restrict__ sc) {
  __shared__ float sm[4][64];
  int wid = threadIdx.x >> 6, lane = threadIdx.x & 63;
  int t = blockIdx.x * 4 + wid;
  if (t < NT) {
    rowaggD(Tx0o, ep0, rp0, rs[OCD0 + t], W1r0, b1r0, mt0L, t, lane, sm[wid],
            a1W, a1b, a1v, sc + 0 * SCSTRIDE, nullptr);
  } else if (t < 2 * NT) {
    int r = t - NT;
    rowaggD(Tx0t, ep2, rp2, rs[OCD2 + r], W1r2, b1r2, m2A, r, lane, sm[wid],
            a1W, a1b, a1v, sc + 1 * SCSTRIDE, aggB0);  // raw = G(S_0) = A_0
  } else {
    int r = t - 2 * NT;
    rowaggD(Tx0t, ep1, rp1, rs[OCD1 + r], W1r1, b1r1, Tx1o, r, lane, sm[wid],
            nullptr, nullptr, nullptr, nullptr, nullptr);
  }
}

// layer-1 combine + GPR heads 0,1 fused with invariant mt0b rowagg
__global__ __launch_bounds__(256) void k_comb1(
    const float* __restrict__ Tx0t, const float* __restrict__ mt0L,
    const float* __restrict__ m2A, const float* __restrict__ Tx1o,
    const float* __restrict__ rs,
    const int* __restrict__ rp0, const EP* __restrict__ ep0,
    const float* __restrict__ W2r0, const float* __restrict__ b2r0,
    const float* __restrict__ a2W, const float* __restrict__ a2b,
    const float* __restrict__ a2v,
    const float* __restrict__ projW, const float* __restrict__ projb,
    const float* __restrict__ gamma,
    float* __restrict__ Tx1t, float* __restrict__ hidden, float* __restrict__ mt0b,
    float* __restrict__ sc) {
  __shared__ float smA[4][64];
  __shared__ float smB[4][64];
  int wid = threadIdx.x >> 6, lane = threadIdx.x & 63;
  int t = blockIdx.x * 4 + wid;
  if (t < NT) {
    int r = t;
    size_t o = (size_t)r * 64 + lane;
    float t0 = Tx0t[o];
    float m0v = mt0L[o];
    float m2v = m2A[o];
    float s0 = scSum(sc, 0, lane) * INV_NT;
    float s1 = scSum(sc, 1, lane) * INV_NT;
    float mx = fmaxf(s0, s1);
    float e0 = expf(s0 - mx), e1 = expf(s1 - mx);
    float inv = 1.0f / (e0 + e1);
    float t1v = e0 * inv * m0v + e1 * inv * m2v;
    Tx1t[o] = t1v;
    smA[wid][lane] = t0;
    smB[wid][lane] = t1v;
    int half = lane >> 5, hl = lane & 31;
    const float* pw = projW + (size_t)half * 2048;
    const float* src = half ? smB[wid] : smA[wid];
    float pa = projb[half * 32 + hl];
#pragma unroll 8
    for (int k = 0; k < 64; ++k)
      pa = fmaf(src[k], pw[k * 32 + hl], pa);
    float part = tanhf(pa) * gamma[hl * (KORD + 1) + half];
#pragma unroll
    for (int d = 16; d >= 1; d >>= 1) part += __shfl_xor(part, d, 64);
    float eta0 = __shfl(part, 0, 64) * (1.0f / 32.0f);
    float eta1 = __shfl(part, 32, 64) * (1.0f / 32.0f);
    hidden[o] = t0 * eta0 + t1v * eta1;
  } else {
    int r = t - NT;
    rowaggD(Tx1o, ep0, rp0, rs[OCD0 + r], W2r0, b2r0, mt0b, r, lane, smA[wid],
            a2W, a2b, a2v, sc + 2 * SCSTRIDE, nullptr);
  }
}

// j=1: blocks<3000 gather S_1 -> A_1 raw + mt2_1 + score slot 3;
// blocks>=3000: invariant g0 = G(mt0b).
__global__ __launch_bounds__(256) void k_iter1(
    const float* __restrict__ Tx1t, const float* __restrict__ mt0b,
    const float* __restrict__ rsd2, const int* __restrict__ rp2,
    const EP* __restrict__ ep2,
    const float* __restrict__ W, const float* __restrict__ bW,
    const float* __restrict__ fcW, const float* __restrict__ fcb,
    const float* __restrict__ av,
    float* __restrict__ mtdst, float* __restrict__ aggB1,
    float* __restrict__ g0, float* __restrict__ scoreNew) {
  __shared__ float sm[4][64];
  int wid = threadIdx.x >> 6, lane = threadIdx.x & 63;
  if (blockIdx.x < 3000) {
    int row = blockIdx.x * 4 + wid;
    rowaggD(Tx1t, ep2, rp2, rsd2[row], W, bW, mtdst, row, lane, sm[wid],
            fcW, fcb, av, scoreNew, aggB1);
  } else {
    int r = blockIdx.x * 4 + wid - NT;
    g0[(size_t)r * 64 + lane] = gatherEP(ep2, rp2[r], rp2[r + 1], mt0b, lane);
  }
}

// Fused GPR iteration j>=2 (ONE dispatch); LDS-broadcast GEMMs.
// Gather issued first so its VMEM latency overlaps the scSum L2 reads.
__global__ __launch_bounds__(256) void k_iterF(
    const float* __restrict__ mt2prev, const float* __restrict__ g0,
    float* __restrict__ agg,  // read A_{j-2}, write A_j (same element, same thread)
    const float* __restrict__ mt0b, const float* __restrict__ Tsrc2,
    float* __restrict__ Tdst,
    const float* __restrict__ rsd2, const int* __restrict__ rp2,
    const EP* __restrict__ ep2,
    const float* __restrict__ W, const float* __restrict__ bW,
    const float* __restrict__ fcW, const float* __restrict__ fcb,
    const float* __restrict__ av,
    const float* __restrict__ sc, int slotPrev, float* __restrict__ scoreNew,
    const float* __restrict__ projW, const float* __restrict__ projb,
    const float* __restrict__ gamma, int kidx,
    float* __restrict__ hidden, float* __restrict__ mtdst) {
  __shared__ float sm[4][64];
  int wid = threadIdx.x >> 6, lane = threadIdx.x & 63;
  float* smrow = sm[wid];
  int r = blockIdx.x * 4 + wid;
  float gm = gatherEP(ep2, rp2[r], rp2[r + 1], mt2prev, lane);
  float s0 = scSum(sc, 2, lane) * INV_NT;
  float s1 = scSum(sc, slotPrev, lane) * INV_NT;
  float mx = fmaxf(s0, s1);
  float e0 = expf(s0 - mx), e1 = expf(s1 - mx);
  float inv = 1.0f / (e0 + e1);
  float tw0 = 2.0f * e0 * inv, tw1 = 2.0f * e1 * inv;
  size_t o = (size_t)r * 64 + lane;
  float aggj = fmaf(tw0, g0[o], fmaf(tw1, gm, -agg[o]));
  agg[o] = aggj;
  smrow[lane] = aggj * rsd2[r];
  float m = bW[lane];
#pragma unroll 8
  for (int k = 0; k < 64; ++k) m = fmaf(smrow[k], W[k * 64 + lane], m);
  mtdst[o] = m;
  smrow[lane] = m;
  float fa = fcb[lane];
#pragma unroll 8
  for (int k = 0; k < 64; ++k) fa = fmaf(smrow[k], fcW[k * 64 + lane], fa);
  float part = waveSum(tanhf(fa) * av[lane]);
  if (lane == 0) atomicAdd(&scoreNew[(blockIdx.x & 63) * 16], part);
  float tj = fmaf(tw0, mt0b[o], fmaf(tw1, mt2prev[o], -Tsrc2[o]));
  Tdst[o] = tj;
  smrow[lane] = tj;
  float eta = gprEta(smrow, projW, projb, gamma, kidx, lane);
  hidden[o] += tj * eta;
}

// T10 fold + h=tanh -> out, logits, loss partial, stage-1 MLP for h and z_p
__global__ __launch_bounds__(256) void k_post1(
    float* __restrict__ hidden, const float* __restrict__ mt0b,
    const float* __restrict__ mt9, const float* __restrict__ T8,
    const float* __restrict__ sc,
    const float* __restrict__ projW, const float* __restrict__ projb,
    const float* __restrict__ gamma,
    const float* __restrict__ z_pre,
    const float* __restrict__ p3W, const float* __restrict__ p3b,
    const float* __restrict__ outW, const float* __restrict__ outb,
    const float* __restrict__ p1W1, const float* __restrict__ p1b1,
    float* __restrict__ outH, float* __restrict__ outLogits,
    float* __restrict__ t1, float* __restrict__ t1z,
    float* __restrict__ lossAcc) {
  __shared__ float smH[4][64];
  __shared__ float smZ[4][64];
  int wid = threadIdx.x >> 6, lane = threadIdx.x & 63;
  int row = blockIdx.x * 4 + wid;
  size_t o = (size_t)row * 64 + lane;
  float s0 = scSum(sc, 2, lane) * INV_NT;
  float s1 = scSum(sc, 11, lane) * INV_NT;
  float mx = fmaxf(s0, s1);
  float e0 = expf(s0 - mx), e1 = expf(s1 - mx);
  float inv = 1.0f / (e0 + e1);
  float tw0 = 2.0f * e0 * inv, tw1 = 2.0f * e1 * inv;
  float t10 = fmaf(tw0, mt0b[o], fmaf(tw1, mt9[o], -T8[o]));
  smH[wid][lane] = t10;
  float eta = gprEta(smH[wid], projW, projb, gamma, KORD, lane);
  float hfin = hidden[o] + t10 * eta;
  hidden[o] = hfin;  // adj reads this
  float hv = tanhf(hfin);
  outH[o] = hv;
  const float* zr = z_pre + (size_t)row * 128;
  float zpv = p3b[lane];
  for (int k = 0; k < 128; ++k) zpv = fmaf(zr[k], p3W[k * 64 + lane], zpv);
  smH[wid][lane] = hv;
  smZ[wid][lane] = zpv;
  float hm = waveSum(hv) * (1.0f / 64.0f);
  float zm = waveSum(zpv) * (1.0f / 64.0f);
  float cv = waveSum((hv - hm) * (zpv - zm)) * (1.0f / 64.0f);
  if (lane == 0) atomicAdd(&lossAcc[(blockIdx.x & 63) * 16], cv);
#pragma unroll
  for (int j = 0; j < 3; ++j) {
    float pj = waveSum(hv * outW[lane * 3 + j]);
    if (lane == 0) outLogits[row * 3 + j] = pj + outb[j];
  }
  float a0 = p1b1[lane], a1 = p1b1[64 + lane];
  float z0 = a0, z1 = a1;
#pragma unroll 4
  for (int k = 0; k < 64; ++k) {
    float hk = smH[wid][k];
    float zk = smZ[wid][k];
    float wlo = p1W1[k * 128 + lane], whi = p1W1[k * 128 + 64 + lane];
    a0 = fmaf(hk, wlo, a0); a1 = fmaf(hk, whi, a1);
    z0 = fmaf(zk, wlo, z0); z1 = fmaf(zk, whi, z1);
  }
  t1[(size_t)row * 128 + lane] = fmaxf(a0, 0.f);
  t1[(size_t)row * 128 + 64 + lane] = fmaxf(a1, 0.f);
  t1z[(size_t)row * 128 + lane] = fmaxf(z0, 0.f);
  t1z[(size_t)row * 128 + 64 + lane] = fmaxf(z1, 0.f);
}

// Fused: blocks [0,NADJ) = C=H@H^T triangular tiles (16-deep k phases with
// register-prefetch software pipeline); blocks >= NADJ = stage-2 MLP + loss.
__global__ __launch_bounds__(256) void k_adjpost(
    const float* __restrict__ H, float* __restrict__ C, int N,
    const float* __restrict__ t1, const float* __restrict__ t1z,
    const float* __restrict__ p1W2, const float* __restrict__ p1b2,
    float* __restrict__ xpre, float* __restrict__ zpre1,
    const float* __restrict__ lossAcc, float* __restrict__ outLoss) {
  __shared__ float sh[4224];  // As = sh[0..2111] (16x132), Bs = sh[2112..4223]
  int b = blockIdx.x;
  if (b < NADJ) {
    int bi = 0, idx = b, rowlen = NB;
    while (idx >= rowlen) { idx -= rowlen; --rowlen; ++bi; }
    int bj = bi + idx;
    int tid = threadIdx.x;
    int tx = tid & 15, ty = tid >> 4;
    int rb = tid & 127, halfq = tid >> 7;  // load indexing
    int gi = bi * 128 + rb;
    int gj = bj * 128 + rb;
    int kk0 = (halfq * 2 + 0) * 4, kk1 = (halfq * 2 + 1) * 4;
    float4 pA0, pA1, pB0, pB1;
    auto ldph = [&](int kt) {
      pA0 = (gi < N) ? *reinterpret_cast<const float4*>(&H[(size_t)gi * 64 + kt + kk0])
                     : make_float4(0.f, 0.f, 0.f, 0.f);
      pA1 = (gi < N) ? *reinterpret_cast<const float4*>(&H[(size_t)gi * 64 + kt + kk1])
                     : make_float4(0.f, 0.f, 0.f, 0.f);
      pB0 = (gj < N) ? *reinterpret_cast<const float4*>(&H[(size_t)gj * 64 + kt + kk0])
                     : make_float4(0.f, 0.f, 0.f, 0.f);
      pB1 = (gj < N) ? *reinterpret_cast<const float4*>(&H[(size_t)gj * 64 + kt + kk1])
                     : make_float4(0.f, 0.f, 0.f, 0.f);
    };
    auto stph = [&]() {
      sh[(kk0 + 0) * 132 + rb] = pA0.x; sh[(kk0 + 1) * 132 + rb] = pA0.y;
      sh[(kk0 + 2) * 132 + rb] = pA0.z; sh[(kk0 + 3) * 132 + rb] = pA0.w;
      sh[(kk1 + 0) * 132 + rb] = pA1.x; sh[(kk1 + 1) * 132 + rb] = pA1.y;
      sh[(kk1 + 2) * 132 + rb] = pA1.z; sh[(kk1 + 3) * 132 + rb] = pA1.w;
      sh[2112 + (kk0 + 0) * 132 + rb] = pB0.x; sh[2112 + (kk0 + 1) * 132 + rb] = pB0.y;
      sh[2112 + (kk0 + 2) * 132 + rb] = pB0.z; sh[2112 + (kk0 + 3) * 132 + rb] = pB0.w;
      sh[2112 + (kk1 + 0) * 132 + rb] = pB1.x; sh[2112 + (kk1 + 1) * 132 + rb] = pB1.y;
      sh[2112 + (kk1 + 2) * 132 + rb] = pB1.z; sh[2112 + (kk1 + 3) * 132 + rb] = pB1.w;
    };
    float acc[8][8] = {};
    ldph(0);
    stph();
    __syncthreads();
    for (int kt = 0; kt < 64; kt += 16) {
      if (kt < 48) ldph(kt + 16);  // prefetch next phase; latency hides under FMA
#pragma unroll 8
      for (int k = 0; k < 16; ++k) {
        float4 a0 = *reinterpret_cast<const float4*>(&sh[k * 132 + ty * 4]);
        float4 a1 = *reinterpret_cast<const float4*>(&sh[k * 132 + 64 + ty * 4]);
        float4 b0 = *reinterpret_cast<const float4*>(&sh[2112 + k * 132 + tx * 4]);
        float4 b1 = *reinterpret_cast<const float4*>(&sh[2112 + k * 132 + 64 + tx * 4]);
        float av[8] = {a0.x, a0.y, a0.z, a0.w, a1.x, a1.y, a1.z, a1.w};
        float bv[8] = {b0.x, b0.y, b0.z, b0.w, b1.x, b1.y, b1.z, b1.w};
#pragma unroll
        for (int i = 0; i < 8; ++i)
#pragma unroll
          for (int j = 0; j < 8; ++j) acc[i][j] = fmaf(av[i], bv[j], acc[i][j]);
      }
      __syncthreads();
      if (kt < 48) {
        stph();
        __syncthreads();
      }
    }
#pragma unroll
    for (int g = 0; g < 2; ++g) {
#pragma unroll
      for (int i = 0; i < 4; ++i) {
        int gr = bi * 128 + g * 64 + ty * 4 + i;
        if (gr >= N) continue;
#pragma unroll
        for (int h = 0; h < 2; ++h) {
          int gc = bj * 128 + h * 64 + tx * 4;
          if (gc >= N) continue;
          nfloat4 vv = {acc[g * 4 + i][h * 4 + 0], acc[g * 4 + i][h * 4 + 1],
                        acc[g * 4 + i][h * 4 + 2], acc[g * 4 + i][h * 4 + 3]};
          *reinterpret_cast<nfloat4*>(&C[(size_t)gr * N + gc]) = vv;
        }
      }
    }
    if (bi != bj) {
      float* T = sh;
      int cc = tid >> 4, f4 = tid & 15;
#pragma unroll
      for (int g = 0; g < 2; ++g) {
#pragma unroll
        for (int h = 0; h < 2; ++h) {
          __syncthreads();
#pragma unroll
          for (int i = 0; i < 4; ++i) {
            int r = ty * 4 + i;
#pragma unroll
            for (int j = 0; j < 4; ++j)
              T[r * 65 + tx * 4 + j] = acc[g * 4 + i][h * 4 + j];
          }
          __syncthreads();
          int gr0 = bi * 128 + g * 64 + f4 * 4;
#pragma unroll
          for (int c0 = 0; c0 < 64; c0 += 16) {
            int c = c0 + cc;
            int gc = bj * 128 + h * 64 + c;
            if (gc < N) {
              nfloat4 v = {T[(f4 * 4 + 0) * 65 + c], T[(f4 * 4 + 1) * 65 + c],
                           T[(f4 * 4 + 2) * 65 + c], T[(f4 * 4 + 3) * 65 + c]};
              *reinterpret_cast<nfloat4*>(&C[(size_t)gc * N + gr0]) = v;
            }
          }
        }
      }
    }
    return;
  }
  // ---- post2 part: stage-1 rows in wave-local LDS, broadcast GEMM ----
  int qb = b - NADJ;  // 0..1499
  if (qb == 0 && threadIdx.x < 64) {
    float v = waveSum(lossAcc[threadIdx.x * 16]);
    if (threadIdx.x == 0) {
      float s = v * (1.0f / NT);
      outLoss[0] = s * s;  // loss_dis1 (1-row HSIC) is exactly 0
    }
  }
  int wid = threadIdx.x >> 6, lane = threadIdx.x & 63;
  int q = qb * 4 + wid;  // 0..5999
  bool isz = q >= 3000;
  int r0 = (isz ? q - 3000 : q) * 4;
  const float* T = isz ? t1z : t1;
  float* D = isz ? zpre1 : xpre;
  float* shp = sh + wid * 520;  // 4 rows x 130 stride (wave-private)
#pragma unroll
  for (int rr = 0; rr < 4; ++rr) {
    shp[rr * 130 + lane] = T[(size_t)(r0 + rr) * 128 + lane];
    shp[rr * 130 + 64 + lane] = T[(size_t)(r0 + rr) * 128 + 64 + lane];
  }
  for (int c0 = 0; c0 < 384; c0 += 64) {
    int c = c0 + lane;
    bool ok = c < 334;
    float bb = ok ? p1b2[c] : 0.f;
    float acc0 = bb, acc1 = bb, acc2 = bb, acc3 = bb;
#pragma unroll 4
    for (int k = 0; k < 128; ++k) {
      float w = ok ? p1W2[k * 334 + c] : 0.f;
      acc0 = fmaf(shp[0 * 130 + k], w, acc0);
      acc1 = fmaf(shp[1 * 130 + k], w, acc1);
      acc2 = fmaf(shp[2 * 130 + k], w, acc2);
      acc3 = fmaf(shp[3 * 130 + k], w, acc3);
    }
    if (ok) {
      D[(size_t)(r0 + 0) * 334 + c] = tanhf(acc0);
      D[(size_t)(r0 + 1) * 334 + c] = tanhf(acc1);
      D[(size_t)(r0 + 2) * 334 + c] = tanhf(acc2);
      D[(size_t)(r0 + 3) * 334 + c] = tanhf(acc3);
    }
  }
}

extern "C" void kernel_launch(void* const* d_in, const int* in_sizes, int n_in,
                              void* d_out, int out_size, void* d_ws, size_t ws_size,
                              hipStream_t stream) {
  const float* features_v1 = (const float*)d_in[0];
  const float* feat_other = (const float*)d_in[1];
  const float* z_pre = (const float*)d_in[2];
  const float* Wt = (const float*)d_in[3];  const float* bt = (const float*)d_in[4];
  const float* Wo = (const float*)d_in[5];  const float* bo = (const float*)d_in[6];
  const float* W1r0 = (const float*)d_in[7];  const float* b1r0 = (const float*)d_in[8];
  const float* W1r1 = (const float*)d_in[9];  const float* b1r1 = (const float*)d_in[10];
  const float* W1r2 = (const float*)d_in[11]; const float* b1r2 = (const float*)d_in[12];
  const float* a1W = (const float*)d_in[13]; const float* a1b = (const float*)d_in[14];
  const float* a1v = (const float*)d_in[15];
  const float* W2r0 = (const float*)d_in[16]; const float* b2r0 = (const float*)d_in[17];
  // d_in[18]/d_in[19] (W2r1/b2r1) feed only the discarded loop out_o — unused.
  const float* W2r2 = (const float*)d_in[20]; const float* b2r2 = (const float*)d_in[21];
  const float* a2W = (const float*)d_in[22]; const float* a2b = (const float*)d_in[23];
  const float* a2v = (const float*)d_in[24];
  const float* projW = (const float*)d_in[25]; const float* projb = (const float*)d_in[26];
  const float* gamma = (const float*)d_in[27];
  const float* p3W = (const float*)d_in[28]; const float* p3b = (const float*)d_in[29];
  const float* p1W1 = (const float*)d_in[30]; const float* p1b1 = (const float*)d_in[31];
  const float* p1W2 = (const float*)d_in[32]; const float* p1b2 = (const float*)d_in[33];
  const float* outW = (const float*)d_in[34]; const float* outb = (const float*)d_in[35];
  const int* sr0 = (const int*)d_in[36]; const int* ds0 = (const int*)d_in[37];
  const int* sr1 = (const int*)d_in[38]; const int* ds1 = (const int*)d_in[39];
  const int* sr2 = (const int*)d_in[40]; const int* ds2 = (const int*)d_in[41];

  float* out = (float*)d_out;
  const size_t LOGITS_OFF = 0;
  const size_t H_OFF = (size_t)NT * 3;
  const size_t XPRE_OFF = H_OFF + (size_t)NT * 64;
  const size_t ZPRE_OFF = XPRE_OFF + (size_t)NT * 334;
  const size_t ADJ_OFF = ZPRE_OFF + (size_t)NT * 334;
  const size_t LOSS_OFF = ADJ_OFF + (size_t)NT * NT;

  float* ws = (float*)d_ws;
  size_t o = 0;
  auto alloc = [&](size_t n) { float* p = ws + o; o += n; return p; };
  float* Tbuf0 = alloc((size_t)NT * 64);   // S_0 (= Tx0t)
  float* Tbuf1 = alloc((size_t)NT * 64);   // S_1
  float* Tbuf2 = alloc((size_t)NT * 64);
  float* Tx0o = alloc((size_t)NO * 64);
  float* Tx1o = alloc((size_t)NO * 64);
  float* mt0L = alloc((size_t)NT * 64);
  float* mt0b = alloc((size_t)NT * 64);
  float* m2A  = alloc((size_t)NT * 64);
  float* m2B  = alloc((size_t)NT * 64);
  float* hidden = alloc((size_t)NT * 64);
  float* t1   = alloc((size_t)NT * 128);
  float* t1z  = alloc((size_t)NT * 128);
  float* g0   = alloc((size_t)NT * 64);   // G(mt0b), loop-invariant
  float* aggB0 = alloc((size_t)NT * 64);  // A_{even}
  float* aggB1 = alloc((size_t)NT * 64);  // A_{odd}
  float* rs   = alloc(96000);
  // score slots 0..11 (1024 floats each, 64 buckets x 16 stride), loss = slot 12
  float* sc   = alloc(13 * SCSTRIDE);  // memset region starts here
  int* cnt = (int*)(ws + o); o += 96000;
  int* fil = (int*)(ws + o); o += 48000;
  int* rp0 = (int*)(ws + o); o += NT + 1;
  int* rp1 = (int*)(ws + o); o += NO + 1;
  int* rp2 = (int*)(ws + o); o += NT + 1;
  int* ctot = (int*)(ws + o); o += 120;
  o = (o + 1) & ~(size_t)1;  // 8-byte align for EP arrays
  EP* ep0 = (EP*)(ws + o); o += (size_t)E0C * 2;
  EP* ep1 = (EP*)(ws + o); o += (size_t)E1C * 2;
  EP* ep2 = (EP*)(ws + o); o += (size_t)E2C * 2;

  // zero accumulators: sc(13*1024) + cnt(96000) + fil(48000), contiguous
  (void)hipMemsetAsync(sc, 0, (13 * SCSTRIDE + 96000 + 48000) * sizeof(float), stream);

  k_histproj<<<2048, 256, 0, stream>>>(sr0, ds0, sr1, ds1, sr2, ds2, cnt,
                                       features_v1, feat_other, Wt, bt, Wo, bo,
                                       Tbuf0, Tx0o);
  k_rsScan<<<48, 1024, 0, stream>>>(cnt, rs, rp0, rp1, rp2, ctot);
  k_rpfix<<<256, 256, 0, stream>>>(rp0, rp1, rp2, ctot);
  k_fill<<<2048, 256, 0, stream>>>(sr0, ds0, sr1, ds1, sr2, ds2, rp0, rp1, rp2,
                                   fil, rs, ep0, ep1, ep2);
  k_layer1<<<12000, 256, 0, stream>>>(Tbuf0, Tx0o, rs,
                                      rp0, ep0, rp1, ep1, rp2, ep2,
                                      W1r0, b1r0, W1r1, b1r1, W1r2, b1r2,
                                      a1W, a1b, a1v, mt0L, m2A, Tx1o, aggB0, sc);
  k_comb1<<<6000, 256, 0, stream>>>(Tbuf0, mt0L, m2A, Tx1o, rs, rp0, ep0,
                                    W2r0, b2r0, a2W, a2b, a2v,
                                    projW, projb, gamma,
                                    Tbuf1, hidden, mt0b, sc);

  float* Tb[3] = {Tbuf0, Tbuf1, Tbuf2};
  float* Mb[2] = {m2A, m2B};
  float* Ab[2] = {aggB0, aggB1};
  const float* rsd2 = rs + OCD2;
  // j=1: gather S_1 -> A_1 + mt2_1 (Mb[1]) + score slot 3; also g0 = G(mt0b)
  k_iter1<<<6000, 256, 0, stream>>>(Tbuf1, mt0b, rsd2, rp2, ep2,
                                    W2r2, b2r2, a2W, a2b, a2v,
                                    Mb[1], aggB1, g0, sc + 3 * SCSTRIDE);
  for (int j = 2; j <= 9; ++j) {
    k_iterF<<<3000, 256, 0, stream>>>(Mb[(j - 1) & 1], g0, Ab[j & 1],
                                      mt0b, Tb[(j - 2) % 3], Tb[j % 3],
                                      rsd2, rp2, ep2, W2r2, b2r2,
                                      a2W, a2b, a2v, sc, 2 + j - 1,
                                      sc + (2 + j) * SCSTRIDE,
                                      projW, projb, gamma, j,
                                      hidden, Mb[j & 1]);
  }
  // S_9 in Tb[0]; S_8 in Tb[2]; mt2_9 in Mb[1]

  k_post1<<<3000, 256, 0, stream>>>(hidden, mt0b, Mb[1], Tb[2], sc,
                                    projW, projb, gamma, z_pre, p3W, p3b,
                                    outW, outb, p1W1, p1b1,
                                    out + H_OFF, out + LOGITS_OFF, t1, t1z,
                                    sc + 12 * SCSTRIDE);
  k_adjpost<<<NADJ + 1500, 256, 0, stream>>>(hidden, out + ADJ_OFF, NT,
                                             t1, t1z, p1W2, p1b2,
                                             out + XPRE_OFF, out + ZPRE_OFF,
                                             sc + 12 * SCSTRIDE, out + LOSS_OFF);
}